// Round 1
// baseline (544.049 us; speedup 1.0000x reference)
//
#include <hip/hip_runtime.h>

#define NN 30000      // nodes
#define NE 150000     // edges per graph
#define KIN 512
#define KHID 512
#define KOUT 256
#define NG 3
#define KCAT (KHID*NG)   // 1536
#define MTILES ((NN + 127) / 128)   // 235

typedef __attribute__((ext_vector_type(8))) __bf16 bf16x8;
typedef __attribute__((ext_vector_type(4))) float  f32x4;

__device__ __forceinline__ unsigned short f2bf(float f) {
    unsigned u = __float_as_uint(f);
    u = (u + 0x7FFFu + ((u >> 16) & 1u)) >> 16;   // round-to-nearest-even
    return (unsigned short)u;
}

__device__ __forceinline__ void gl_lds16(const void* g, void* l) {
    __builtin_amdgcn_global_load_lds(
        (const __attribute__((address_space(1))) void*)g,
        (__attribute__((address_space(3))) void*)l, 16, 0, 0);
}

// ---------- degree histogram ----------
__global__ void k_count(const int* __restrict__ e0, const int* __restrict__ e1,
                        const int* __restrict__ e2, int* cnt_out, int* cnt_in) {
    int idx = blockIdx.x * 256 + threadIdx.x;
    if (idx >= NG * NE) return;
    int g = idx / NE, e = idx - g * NE;
    const int* ed = (g == 0) ? e0 : ((g == 1) ? e1 : e2);
    atomicAdd(&cnt_out[g * NN + ed[e]], 1);        // src row
    atomicAdd(&cnt_in [g * NN + ed[NE + e]], 1);   // dst row
}

// ---------- rsqrt(clip(deg,1)) ----------
__global__ void k_rs(const int* cnt_out, const int* cnt_in, float* rs_out, float* rs_in) {
    int idx = blockIdx.x * 256 + threadIdx.x;
    if (idx >= NG * NN) return;
    int co = cnt_out[idx]; if (co < 1) co = 1;
    int ci = cnt_in [idx]; if (ci < 1) ci = 1;
    rs_out[idx] = rsqrtf((float)co);
    rs_in [idx] = rsqrtf((float)ci);
}

// ---------- exclusive scan of in-degrees -> CSR row offsets (one block/graph) ----------
__global__ void k_scan(const int* __restrict__ cnt_in, int* __restrict__ row_off) {
    int g = blockIdx.x;
    const int* c = cnt_in + g * NN;
    int* ro = row_off + g * (NN + 1);
    __shared__ int wsum[16];
    int tid = threadIdx.x, lane = tid & 63, wid = tid >> 6;
    int base = 0;
    for (int start = 0; start < NN; start += 1024) {
        int i = start + tid;
        int v = (i < NN) ? c[i] : 0;
        int inc = v;
        #pragma unroll
        for (int o = 1; o < 64; o <<= 1) {
            int n = __shfl_up(inc, o, 64);
            if (lane >= o) inc += n;
        }
        if (lane == 63) wsum[wid] = inc;
        __syncthreads();
        int wb = 0;
        for (int k = 0; k < wid; k++) wb += wsum[k];
        if (i < NN) ro[i] = base + wb + inc - v;
        int tot = 0;
        for (int k = 0; k < 16; k++) tot += wsum[k];
        base += tot;
        __syncthreads();
    }
    if (tid == 0) ro[NN] = base;
}

// ---------- CSR fill ----------
__global__ void k_fill(const int* __restrict__ e0, const int* __restrict__ e1,
                       const int* __restrict__ e2, const int* __restrict__ row_off,
                       int* cursor, int* __restrict__ csr) {
    int idx = blockIdx.x * 256 + threadIdx.x;
    if (idx >= NG * NE) return;
    int g = idx / NE, e = idx - g * NE;
    const int* ed = (g == 0) ? e0 : ((g == 1) ? e1 : e2);
    int s = ed[e], d = ed[NE + e];
    int pos = atomicAdd(&cursor[g * NN + d], 1);
    csr[g * NE + row_off[g * (NN + 1) + d] + pos] = s;
}

// ---------- weights -> bf16 transposed [n][k]; softmax(alphas) ----------
__global__ void k_prep(const float* __restrict__ W0, const float* __restrict__ W1,
                       const float* __restrict__ W2, const float* __restrict__ Wlin,
                       const float* __restrict__ alphas,
                       unsigned short* __restrict__ Wt, unsigned short* __restrict__ Wlt,
                       float* __restrict__ a) {
    int idx = blockIdx.x * 256 + threadIdx.x;
    if (idx == 0) {
        float m = fmaxf(alphas[0], fmaxf(alphas[1], alphas[2]));
        float ex0 = expf(alphas[0] - m), ex1 = expf(alphas[1] - m), ex2 = expf(alphas[2] - m);
        float s = ex0 + ex1 + ex2;
        a[0] = ex0 / s; a[1] = ex1 / s; a[2] = ex2 / s;
    }
    if (idx < NG * KIN * KHID) {
        int g = idx / (KIN * KHID);
        int r = idx - g * (KIN * KHID);
        int k = r >> 9, n = r & 511;                    // W[k][n], read coalesced
        const float* W = (g == 0) ? W0 : ((g == 1) ? W1 : W2);
        Wt[(size_t)g * KIN * KHID + (size_t)n * KIN + k] = f2bf(W[r]);
    } else {
        int r = idx - NG * KIN * KHID;
        if (r < KCAT * KOUT) {
            int k = r >> 8, n = r & 255;                // Wlin[k][n]
            Wlt[(size_t)n * KCAT + k] = f2bf(Wlin[r]);
        }
    }
}

// ---------- aggregation: y[d] = rs_in[d] * sum_e rs_out[s_e] * x[s_e]  (bf16 out) ----------
__global__ __launch_bounds__(256) void k_agg(const float* __restrict__ x,
        const int* __restrict__ csr, const int* __restrict__ row_off,
        const float* __restrict__ rs_out, const float* __restrict__ rs_in,
        unsigned short* __restrict__ y, int g) {
    int d    = blockIdx.x * 4 + (threadIdx.x >> 6);    // one wave per node
    int lane = threadIdx.x & 63;
    int beg = row_off[g * (NN + 1) + d];
    int end = row_off[g * (NN + 1) + d + 1];
    const int* cs = csr + g * NE;
    float a0=0,a1=0,a2=0,a3=0,a4=0,a5=0,a6=0,a7=0;
    const float* xb = x + lane * 8;
    for (int e = beg; e < end; e++) {
        int s = cs[e];
        float wsc = rs_out[g * NN + s];
        const float4* xr = (const float4*)(xb + (size_t)s * KIN);
        float4 v0 = xr[0], v1 = xr[1];
        a0 += wsc * v0.x; a1 += wsc * v0.y; a2 += wsc * v0.z; a3 += wsc * v0.w;
        a4 += wsc * v1.x; a5 += wsc * v1.y; a6 += wsc * v1.z; a7 += wsc * v1.w;
    }
    float ri = rs_in[g * NN + d];
    uint4 pk;
    pk.x = (unsigned)f2bf(a0 * ri) | ((unsigned)f2bf(a1 * ri) << 16);
    pk.y = (unsigned)f2bf(a2 * ri) | ((unsigned)f2bf(a3 * ri) << 16);
    pk.z = (unsigned)f2bf(a4 * ri) | ((unsigned)f2bf(a5 * ri) << 16);
    pk.w = (unsigned)f2bf(a6 * ri) | ((unsigned)f2bf(a7 * ri) << 16);
    *(uint4*)(y + (size_t)d * KIN + lane * 8) = pk;
}

// ---------- 128x128 bf16 MFMA GEMM (m97 structure), templated epilogue ----------
// A: [M(clamped 30000) x KDIM] bf16 row-major.  Bt: [Ncols x KDIM] bf16 (B transposed).
// TANH: out_bf16[row*KCAT + g*KHID + col] = tanh(a[g] * (acc + bias[col]))
// else: out_f32[row*KOUT + col] = acc + bias[col]
template<int KDIM, bool TANH>
__global__ __launch_bounds__(256) void k_gemm(const unsigned short* __restrict__ A,
        const unsigned short* __restrict__ Bt, const float* __restrict__ bias,
        const float* __restrict__ a_ptr, int g,
        unsigned short* __restrict__ Tout, float* __restrict__ Fout) {
    __shared__ __align__(16) unsigned short As[128 * 32];
    __shared__ __align__(16) unsigned short Bs[128 * 32];
    int m0 = blockIdx.x * 128;
    int n0 = blockIdx.y * 128;
    int tid = threadIdx.x;
    int lane = tid & 63;
    int w = tid >> 6;

    f32x4 acc[4][4];
    #pragma unroll
    for (int i = 0; i < 4; i++)
        #pragma unroll
        for (int j = 0; j < 4; j++) acc[i][j] = (f32x4){0.f, 0.f, 0.f, 0.f};

    int mbase = (w & 1) * 64;
    int nbase = (w >> 1) * 64;
    int mf = mbase + (lane & 15);
    int nf = nbase + (lane & 15);
    int kq = (lane >> 4) * 8;

    // staging: 512 16B-chunks per tile, 2 per thread; LDS dense [row][32] bf16
    int c0 = tid, c1 = tid + 256;
    int ar0 = c0 >> 2, ak0 = (c0 & 3) * 8;
    int ar1 = c1 >> 2, ak1 = (c1 & 3) * 8;
    int grow0 = m0 + ar0; if (grow0 > NN - 1) grow0 = NN - 1;   // clamp tail rows
    int grow1 = m0 + ar1; if (grow1 > NN - 1) grow1 = NN - 1;
    const unsigned short* Ag0 = A + (size_t)grow0 * KDIM + ak0;
    const unsigned short* Ag1 = A + (size_t)grow1 * KDIM + ak1;
    const unsigned short* Bg0 = Bt + (size_t)(n0 + ar0) * KDIM + ak0;
    const unsigned short* Bg1 = Bt + (size_t)(n0 + ar1) * KDIM + ak1;
    unsigned short* Al0 = &As[c0 * 8];
    unsigned short* Al1 = &As[c1 * 8];
    unsigned short* Bl0 = &Bs[c0 * 8];
    unsigned short* Bl1 = &Bs[c1 * 8];

    for (int k0 = 0; k0 < KDIM; k0 += 32) {
        __syncthreads();
        gl_lds16(Ag0 + k0, Al0);
        gl_lds16(Ag1 + k0, Al1);
        gl_lds16(Bg0 + k0, Bl0);
        gl_lds16(Bg1 + k0, Bl1);
        __syncthreads();
        bf16x8 af[4], bf[4];
        #pragma unroll
        for (int mi = 0; mi < 4; mi++) af[mi] = *(const bf16x8*)&As[(mf + mi * 16) * 32 + kq];
        #pragma unroll
        for (int ni = 0; ni < 4; ni++) bf[ni] = *(const bf16x8*)&Bs[(nf + ni * 16) * 32 + kq];
        #pragma unroll
        for (int mi = 0; mi < 4; mi++)
            #pragma unroll
            for (int ni = 0; ni < 4; ni++)
                acc[mi][ni] = __builtin_amdgcn_mfma_f32_16x16x32_bf16(af[mi], bf[ni], acc[mi][ni], 0, 0, 0);
    }

    float ascale = TANH ? a_ptr[g] : 0.f;
    int rb = mbase + (lane >> 4) * 4;
    #pragma unroll
    for (int mi = 0; mi < 4; mi++) {
        #pragma unroll
        for (int r = 0; r < 4; r++) {
            int row = m0 + rb + mi * 16 + r;
            if (row < NN) {
                #pragma unroll
                for (int ni = 0; ni < 4; ni++) {
                    int col = n0 + nbase + ni * 16 + (lane & 15);
                    float v = acc[mi][ni][r] + bias[col];
                    if (TANH) {
                        Tout[(size_t)row * KCAT + g * KHID + col] = f2bf(tanhf(ascale * v));
                    } else {
                        Fout[(size_t)row * KOUT + col] = v;
                    }
                }
            }
        }
    }
}

extern "C" void kernel_launch(void* const* d_in, const int* in_sizes, int n_in,
                              void* d_out, int out_size, void* d_ws, size_t ws_size,
                              hipStream_t stream) {
    const float* x      = (const float*)d_in[0];
    const int*   e0     = (const int*)  d_in[1];
    const float* W0     = (const float*)d_in[2];
    const float* b0     = (const float*)d_in[3];
    const int*   e1     = (const int*)  d_in[4];
    const float* W1     = (const float*)d_in[5];
    const float* b1     = (const float*)d_in[6];
    const int*   e2     = (const int*)  d_in[7];
    const float* W2     = (const float*)d_in[8];
    const float* b2     = (const float*)d_in[9];
    const float* alphas = (const float*)d_in[10];
    const float* Wlin   = (const float*)d_in[11];
    const float* blin   = (const float*)d_in[12];
    float* out = (float*)d_out;

    char* ws = (char*)d_ws;
    size_t off = 0;
    auto alloc = [&](size_t bytes) -> void* {
        void* p = ws + off;
        off = (off + bytes + 255) & ~(size_t)255;
        return p;
    };
    int*   cnt_out = (int*)  alloc((size_t)NG * NN * 4);
    int*   cnt_in  = (int*)  alloc((size_t)NG * NN * 4);
    int*   cursor  = (int*)  alloc((size_t)NG * NN * 4);
    int*   row_off = (int*)  alloc((size_t)NG * (NN + 1) * 4);
    int*   csr     = (int*)  alloc((size_t)NG * NE * 4);
    float* rs_out  = (float*)alloc((size_t)NG * NN * 4);
    float* rs_in   = (float*)alloc((size_t)NG * NN * 4);
    float* aptr    = (float*)alloc(16);
    unsigned short* Wt  = (unsigned short*)alloc((size_t)NG * KIN * KHID * 2);
    unsigned short* Wlt = (unsigned short*)alloc((size_t)KCAT * KOUT * 2);
    unsigned short* y   = (unsigned short*)alloc((size_t)NN * KIN * 2);
    unsigned short* t   = (unsigned short*)alloc((size_t)NN * KCAT * 2);

    // zero the three contiguous int counter arrays (ws is poisoned 0xAA pre-call)
    hipMemsetAsync(cnt_out, 0, (size_t)((char*)cursor - (char*)cnt_out) + (size_t)NG * NN * 4, stream);

    k_count<<<(NG * NE + 255) / 256, 256, 0, stream>>>(e0, e1, e2, cnt_out, cnt_in);
    k_rs<<<(NG * NN + 255) / 256, 256, 0, stream>>>(cnt_out, cnt_in, rs_out, rs_in);
    k_scan<<<NG, 1024, 0, stream>>>(cnt_in, row_off);
    k_fill<<<(NG * NE + 255) / 256, 256, 0, stream>>>(e0, e1, e2, row_off, cursor, csr);
    int prep_elems = NG * KIN * KHID + KCAT * KOUT;
    k_prep<<<(prep_elems + 255) / 256, 256, 0, stream>>>(W0, W1, W2, Wlin, alphas, Wt, Wlt, aptr);

    dim3 g1grid(MTILES, KHID / 128);
    for (int g = 0; g < NG; g++) {
        k_agg<<<NN / 4, 256, 0, stream>>>(x, csr, row_off, rs_out, rs_in, y, g);
        const float* bg = (g == 0) ? b0 : ((g == 1) ? b1 : b2);
        k_gemm<KIN, true><<<g1grid, 256, 0, stream>>>(
            y, Wt + (size_t)g * KIN * KHID, bg, aptr, g, t, nullptr);
    }
    dim3 g2grid(MTILES, KOUT / 128);
    k_gemm<KCAT, false><<<g2grid, 256, 0, stream>>>(t, Wlt, blin, nullptr, 0, nullptr, out);
}

// Round 2
// 479.298 us; speedup vs baseline: 1.1351x; 1.1351x over previous
//
#include <hip/hip_runtime.h>

#define NN 30000      // nodes
#define NE 150000     // edges per graph
#define KIN 512
#define KHID 512
#define KOUT 256
#define NG 3
#define KCAT (KHID*NG)   // 1536
#define MTILES ((NN + 127) / 128)   // 235

typedef __attribute__((ext_vector_type(8))) __bf16 bf16x8;
typedef __attribute__((ext_vector_type(4))) float  f32x4;
typedef __attribute__((ext_vector_type(8))) unsigned short u16x8;

__device__ __forceinline__ unsigned short f2bf(float f) {
    unsigned u = __float_as_uint(f);
    u = (u + 0x7FFFu + ((u >> 16) & 1u)) >> 16;   // round-to-nearest-even
    return (unsigned short)u;
}
__device__ __forceinline__ float bf2f(unsigned short u) {
    return __uint_as_float((unsigned)u << 16);
}
__device__ __forceinline__ void gl_lds16(const void* g, void* l) {
    __builtin_amdgcn_global_load_lds(
        (const __attribute__((address_space(1))) void*)g,
        (__attribute__((address_space(3))) void*)l, 16, 0, 0);
}

// ---------- degree histogram ----------
__global__ void k_count(const int* __restrict__ e0, const int* __restrict__ e1,
                        const int* __restrict__ e2, int* cnt_out, int* cnt_in) {
    int idx = blockIdx.x * 256 + threadIdx.x;
    if (idx >= NG * NE) return;
    int g = idx / NE, e = idx - g * NE;
    const int* ed = (g == 0) ? e0 : ((g == 1) ? e1 : e2);
    atomicAdd(&cnt_out[g * NN + ed[e]], 1);        // src row
    atomicAdd(&cnt_in [g * NN + ed[NE + e]], 1);   // dst row
}

// ---------- rsqrt(clip(deg,1)) ----------
__global__ void k_rs(const int* cnt_out, const int* cnt_in, float* rs_out, float* rs_in) {
    int idx = blockIdx.x * 256 + threadIdx.x;
    if (idx >= NG * NN) return;
    int co = cnt_out[idx]; if (co < 1) co = 1;
    int ci = cnt_in [idx]; if (ci < 1) ci = 1;
    rs_out[idx] = rsqrtf((float)co);
    rs_in [idx] = rsqrtf((float)ci);
}

// ---------- exclusive scan of in-degrees -> CSR row offsets (one block/graph) ----------
__global__ void k_scan(const int* __restrict__ cnt_in, int* __restrict__ row_off) {
    int g = blockIdx.x;
    const int* c = cnt_in + g * NN;
    int* ro = row_off + g * (NN + 1);
    __shared__ int wsum[16];
    int tid = threadIdx.x, lane = tid & 63, wid = tid >> 6;
    int base = 0;
    for (int start = 0; start < NN; start += 1024) {
        int i = start + tid;
        int v = (i < NN) ? c[i] : 0;
        int inc = v;
        #pragma unroll
        for (int o = 1; o < 64; o <<= 1) {
            int n = __shfl_up(inc, o, 64);
            if (lane >= o) inc += n;
        }
        if (lane == 63) wsum[wid] = inc;
        __syncthreads();
        int wb = 0;
        for (int k = 0; k < wid; k++) wb += wsum[k];
        if (i < NN) ro[i] = base + wb + inc - v;
        int tot = 0;
        for (int k = 0; k < 16; k++) tot += wsum[k];
        base += tot;
        __syncthreads();
    }
    if (tid == 0) ro[NN] = base;
}

// ---------- CSR fill ----------
__global__ void k_fill(const int* __restrict__ e0, const int* __restrict__ e1,
                       const int* __restrict__ e2, const int* __restrict__ row_off,
                       int* cursor, int* __restrict__ csr) {
    int idx = blockIdx.x * 256 + threadIdx.x;
    if (idx >= NG * NE) return;
    int g = idx / NE, e = idx - g * NE;
    const int* ed = (g == 0) ? e0 : ((g == 1) ? e1 : e2);
    int s = ed[e], d = ed[NE + e];
    int pos = atomicAdd(&cursor[g * NN + d], 1);
    csr[g * NE + row_off[g * (NN + 1) + d] + pos] = s;
}

// ---------- softmax(alphas) + pack branch biases contiguous ----------
__global__ void k_misc(const float* __restrict__ alphas,
                       const float* __restrict__ b0, const float* __restrict__ b1,
                       const float* __restrict__ b2, float* __restrict__ aptr,
                       float* __restrict__ bcat) {
    int idx = blockIdx.x * 256 + threadIdx.x;
    if (idx < NG * KHID) {
        int g = idx >> 9;
        const float* b = (g == 0) ? b0 : ((g == 1) ? b1 : b2);
        bcat[idx] = b[idx & 511];
    }
    if (idx == 0) {
        float m = fmaxf(alphas[0], fmaxf(alphas[1], alphas[2]));
        float ex0 = expf(alphas[0] - m), ex1 = expf(alphas[1] - m), ex2 = expf(alphas[2] - m);
        float s = ex0 + ex1 + ex2;
        aptr[0] = ex0 / s; aptr[1] = ex1 / s; aptr[2] = ex2 / s;
    }
}

// ---------- weights -> bf16 transposed [n][k], coalesced via 32x32 LDS tile ----------
__global__ __launch_bounds__(256) void k_wt(const float* __restrict__ W0,
        const float* __restrict__ W1, const float* __restrict__ W2,
        const float* __restrict__ Wlin,
        unsigned short* __restrict__ Wt, unsigned short* __restrict__ Wlt) {
    __shared__ float Ls[32][33];
    int bid = blockIdx.x;
    const float* src; unsigned short* dst; int ncols, kdim, k0, n0;
    if (bid < NG * 256) {                 // 3 x (16x16) tiles for the 512x512 W's
        int g = bid >> 8, t = bid & 255;
        int kt = t >> 4, nt = t & 15;
        src = (g == 0) ? W0 : ((g == 1) ? W1 : W2);
        dst = Wt + (size_t)g * KIN * KHID;
        ncols = KHID; kdim = KIN; k0 = kt * 32; n0 = nt * 32;
    } else {                              // Wlin: 48 x 8 tiles (1536 x 256)
        int t = bid - NG * 256;
        int kt = t % 48, nt = t / 48;
        src = Wlin; dst = Wlt; ncols = KOUT; kdim = KCAT; k0 = kt * 32; n0 = nt * 32;
    }
    int tid = threadIdx.x;
    int r = tid >> 3, c4 = (tid & 7) * 4;
    float4 v = *(const float4*)(src + (size_t)(k0 + r) * ncols + n0 + c4);
    Ls[r][c4 + 0] = v.x; Ls[r][c4 + 1] = v.y; Ls[r][c4 + 2] = v.z; Ls[r][c4 + 3] = v.w;
    __syncthreads();
    int nr = tid >> 3, kc = (tid & 7) * 4;
    ushort4 o;
    o.x = f2bf(Ls[kc + 0][nr]); o.y = f2bf(Ls[kc + 1][nr]);
    o.z = f2bf(Ls[kc + 2][nr]); o.w = f2bf(Ls[kc + 3][nr]);
    *(ushort4*)(dst + (size_t)(n0 + nr) * kdim + k0 + kc) = o;
}

// ---------- x -> bf16 (halves aggregation gather traffic) ----------
__global__ void k_xbf(const float* __restrict__ x, unsigned short* __restrict__ xb) {
    size_t i = ((size_t)blockIdx.x * 256 + threadIdx.x) * 8;   // 15.36M elems, grid 7500 exact
    float4 v0 = *(const float4*)(x + i);
    float4 v1 = *(const float4*)(x + i + 4);
    uint4 pk;
    pk.x = (unsigned)f2bf(v0.x) | ((unsigned)f2bf(v0.y) << 16);
    pk.y = (unsigned)f2bf(v0.z) | ((unsigned)f2bf(v0.w) << 16);
    pk.z = (unsigned)f2bf(v1.x) | ((unsigned)f2bf(v1.y) << 16);
    pk.w = (unsigned)f2bf(v1.z) | ((unsigned)f2bf(v1.w) << 16);
    *(uint4*)(xb + i) = pk;
}

// ---------- aggregation (bf16 x): y[d] = rs_in[d] * sum rs_out[s]*x[s] ----------
__global__ __launch_bounds__(256) void k_agg_bf(const unsigned short* __restrict__ xb,
        const int* __restrict__ csr, const int* __restrict__ row_off,
        const float* __restrict__ rs_out, const float* __restrict__ rs_in,
        unsigned short* __restrict__ y, size_t ystride, int gbase) {
    int g    = gbase + blockIdx.z;
    int d    = blockIdx.x * 4 + (threadIdx.x >> 6);    // one wave per node
    int lane = threadIdx.x & 63;
    int beg = row_off[g * (NN + 1) + d];
    int end = row_off[g * (NN + 1) + d + 1];
    const int* cs = csr + g * NE;
    float a0=0,a1=0,a2=0,a3=0,a4=0,a5=0,a6=0,a7=0;
    const unsigned short* xbl = xb + lane * 8;
    for (int e = beg; e < end; e++) {
        int s = cs[e];
        float wsc = rs_out[g * NN + s];
        u16x8 v = *(const u16x8*)(xbl + (size_t)s * KIN);
        a0 += wsc * bf2f(v[0]); a1 += wsc * bf2f(v[1]);
        a2 += wsc * bf2f(v[2]); a3 += wsc * bf2f(v[3]);
        a4 += wsc * bf2f(v[4]); a5 += wsc * bf2f(v[5]);
        a6 += wsc * bf2f(v[6]); a7 += wsc * bf2f(v[7]);
    }
    float ri = rs_in[g * NN + d];
    uint4 pk;
    pk.x = (unsigned)f2bf(a0 * ri) | ((unsigned)f2bf(a1 * ri) << 16);
    pk.y = (unsigned)f2bf(a2 * ri) | ((unsigned)f2bf(a3 * ri) << 16);
    pk.z = (unsigned)f2bf(a4 * ri) | ((unsigned)f2bf(a5 * ri) << 16);
    pk.w = (unsigned)f2bf(a6 * ri) | ((unsigned)f2bf(a7 * ri) << 16);
    *(uint4*)(y + (size_t)g * ystride + (size_t)d * KIN + lane * 8) = pk;
}

// ---------- aggregation (fp32 x fallback, low-ws tier) ----------
__global__ __launch_bounds__(256) void k_agg_f32(const float* __restrict__ x,
        const int* __restrict__ csr, const int* __restrict__ row_off,
        const float* __restrict__ rs_out, const float* __restrict__ rs_in,
        unsigned short* __restrict__ y, int g) {
    int d    = blockIdx.x * 4 + (threadIdx.x >> 6);
    int lane = threadIdx.x & 63;
    int beg = row_off[g * (NN + 1) + d];
    int end = row_off[g * (NN + 1) + d + 1];
    const int* cs = csr + g * NE;
    float a0=0,a1=0,a2=0,a3=0,a4=0,a5=0,a6=0,a7=0;
    const float* xb = x + lane * 8;
    for (int e = beg; e < end; e++) {
        int s = cs[e];
        float wsc = rs_out[g * NN + s];
        const float4* xr = (const float4*)(xb + (size_t)s * KIN);
        float4 v0 = xr[0], v1 = xr[1];
        a0 += wsc * v0.x; a1 += wsc * v0.y; a2 += wsc * v0.z; a3 += wsc * v0.w;
        a4 += wsc * v1.x; a5 += wsc * v1.y; a6 += wsc * v1.z; a7 += wsc * v1.w;
    }
    float ri = rs_in[g * NN + d];
    uint4 pk;
    pk.x = (unsigned)f2bf(a0 * ri) | ((unsigned)f2bf(a1 * ri) << 16);
    pk.y = (unsigned)f2bf(a2 * ri) | ((unsigned)f2bf(a3 * ri) << 16);
    pk.z = (unsigned)f2bf(a4 * ri) | ((unsigned)f2bf(a5 * ri) << 16);
    pk.w = (unsigned)f2bf(a6 * ri) | ((unsigned)f2bf(a7 * ri) << 16);
    *(uint4*)(y + (size_t)d * KIN + lane * 8) = pk;
}

// ---------- 128xNT bf16 MFMA GEMM (m97 structure), templated epilogue ----------
// A: [rows x KDIM] bf16 row-major (per-z offset agstride). Bt: [n][k] bf16.
// TANH: Tout[row*KCAT + g*KHID + col] = bf16(tanh(a[g]*(acc+bias)))
// else: Fout[row*KOUT + col] = acc + bias
template<int KDIM, int NT, bool TANH>
__global__ __launch_bounds__(256) void k_gemm(const unsigned short* __restrict__ A,
        size_t agstride, const unsigned short* __restrict__ Bt,
        const float* __restrict__ bias, const float* __restrict__ aptr, int gbase,
        unsigned short* __restrict__ Tout, float* __restrict__ Fout) {
    constexpr int NF = NT / 32;                      // n-fragments per wave
    __shared__ __align__(16) unsigned short As[128 * 32];
    __shared__ __align__(16) unsigned short Bs[NT * 32];
    int g = gbase + blockIdx.z;
    const unsigned short* Ab = A + (size_t)g * agstride;
    const unsigned short* Bb = TANH ? (Bt + (size_t)g * KIN * KHID) : Bt;
    const float* bb = TANH ? (bias + g * KHID) : bias;
    int m0 = blockIdx.x * 128;
    int n0 = blockIdx.y * NT;
    int tid = threadIdx.x, lane = tid & 63, w = tid >> 6;

    f32x4 acc[4][NF];
    #pragma unroll
    for (int i = 0; i < 4; i++)
        #pragma unroll
        for (int j = 0; j < NF; j++) acc[i][j] = (f32x4){0.f, 0.f, 0.f, 0.f};

    int mbase = (w & 1) * 64;
    int nbase = (w >> 1) * (NT / 2);
    int mf = mbase + (lane & 15);
    int nf = nbase + (lane & 15);
    int kq = (lane >> 4) * 8;

    // staging chunks of 8 shorts: A has 512 (2/thread), B has NT*4
    int ar0 = tid >> 2, ak0 = (tid & 3) * 8;
    int ar1 = ar0 + 64;
    int ga0 = m0 + ar0; if (ga0 >= NN) ga0 = NN - 1;
    int ga1 = m0 + ar1; if (ga1 >= NN) ga1 = NN - 1;
    const unsigned short* Ag0 = Ab + (size_t)ga0 * KDIM + ak0;
    const unsigned short* Ag1 = Ab + (size_t)ga1 * KDIM + ak0;
    const unsigned short* Bg0 = Bb + (size_t)(n0 + ar0) * KDIM + ak0;
    const unsigned short* Bg1 = Bb + (size_t)(n0 + ar1) * KDIM + ak0;
    unsigned short* Al0 = &As[tid * 8];
    unsigned short* Al1 = &As[(tid + 256) * 8];
    unsigned short* Bl0 = &Bs[tid * 8];
    unsigned short* Bl1 = &Bs[(tid + 256) * 8];

    for (int k0 = 0; k0 < KDIM; k0 += 32) {
        __syncthreads();
        gl_lds16(Ag0 + k0, Al0);
        gl_lds16(Ag1 + k0, Al1);
        gl_lds16(Bg0 + k0, Bl0);
        if constexpr (NT == 128) gl_lds16(Bg1 + k0, Bl1);
        __syncthreads();
        bf16x8 af[4], bfr[NF];
        #pragma unroll
        for (int mi = 0; mi < 4; mi++) af[mi] = *(const bf16x8*)&As[(mf + mi * 16) * 32 + kq];
        #pragma unroll
        for (int ni = 0; ni < NF; ni++) bfr[ni] = *(const bf16x8*)&Bs[(nf + ni * 16) * 32 + kq];
        #pragma unroll
        for (int mi = 0; mi < 4; mi++)
            #pragma unroll
            for (int ni = 0; ni < NF; ni++)
                acc[mi][ni] = __builtin_amdgcn_mfma_f32_16x16x32_bf16(af[mi], bfr[ni], acc[mi][ni], 0, 0, 0);
    }

    float ascale = TANH ? aptr[g] : 0.f;
    int rb = mbase + (lane >> 4) * 4;
    #pragma unroll
    for (int mi = 0; mi < 4; mi++) {
        #pragma unroll
        for (int r = 0; r < 4; r++) {
            int row = m0 + rb + mi * 16 + r;
            if (row < NN) {
                #pragma unroll
                for (int ni = 0; ni < NF; ni++) {
                    int col = n0 + nbase + ni * 16 + (lane & 15);
                    float v = acc[mi][ni][r] + bb[col - n0 + (TANH ? n0 : n0)];  // bb indexed by col within this branch
                    // note: for TANH bb = bcat+g*KHID, col in [0,KHID); for final bb = blin, col in [0,KOUT)
                    v = acc[mi][ni][r] + bb[col];
                    if (TANH) {
                        Tout[(size_t)row * KCAT + g * KHID + col] = f2bf(tanhf(ascale * v));
                    } else {
                        Fout[(size_t)row * KOUT + col] = v;
                    }
                }
            }
        }
    }
}

extern "C" void kernel_launch(void* const* d_in, const int* in_sizes, int n_in,
                              void* d_out, int out_size, void* d_ws, size_t ws_size,
                              hipStream_t stream) {
    const float* x      = (const float*)d_in[0];
    const int*   e0     = (const int*)  d_in[1];
    const float* W0     = (const float*)d_in[2];
    const float* b0     = (const float*)d_in[3];
    const int*   e1     = (const int*)  d_in[4];
    const float* W1     = (const float*)d_in[5];
    const float* b1     = (const float*)d_in[6];
    const int*   e2     = (const int*)  d_in[7];
    const float* W2     = (const float*)d_in[8];
    const float* b2     = (const float*)d_in[9];
    const float* alphas = (const float*)d_in[10];
    const float* Wlin   = (const float*)d_in[11];
    const float* blin   = (const float*)d_in[12];
    float* out = (float*)d_out;

    char* ws = (char*)d_ws;
    size_t off = 0;
    auto alloc = [&](size_t bytes) -> void* {
        void* p = ws + off;
        off = (off + bytes + 255) & ~(size_t)255;
        return p;
    };
    int*   cnt_out = (int*)  alloc((size_t)NG * NN * 4);
    int*   cnt_in  = (int*)  alloc((size_t)NG * NN * 4);
    int*   cursor  = (int*)  alloc((size_t)NG * NN * 4);
    int*   row_off = (int*)  alloc((size_t)NG * (NN + 1) * 4);
    int*   csr     = (int*)  alloc((size_t)NG * NE * 4);
    float* rs_out  = (float*)alloc((size_t)NG * NN * 4);
    float* rs_in   = (float*)alloc((size_t)NG * NN * 4);
    float* aptr    = (float*)alloc(16);
    float* bcat    = (float*)alloc((size_t)NG * KHID * 4);
    unsigned short* Wt  = (unsigned short*)alloc((size_t)NG * KIN * KHID * 2);
    unsigned short* Wlt = (unsigned short*)alloc((size_t)KCAT * KOUT * 2);

    const size_t SZ_Y1 = (size_t)NN * KIN * 2;     // 30.72 MB
    const size_t SZ_T  = (size_t)NN * KCAT * 2;    // 92.16 MB
    size_t remaining = (ws_size > off) ? (ws_size - off) : 0;
    int mode;                                       // 2=batched(bf16 agg), 1=loop(bf16 agg), 0=loop(f32 agg)
    if      (remaining >= 3 * SZ_Y1 + SZ_T + 8192)          mode = 2;  // t aliases xb
    else if (remaining >= SZ_Y1 + SZ_Y1 + SZ_T + 8192)      mode = 1;
    else                                                    mode = 0;

    unsigned short *y, *xb, *t;
    if (mode == 2) {
        y  = (unsigned short*)alloc(3 * SZ_Y1);
        t  = (unsigned short*)alloc(SZ_T);
        xb = t;                                    // xb dead before t is written
    } else if (mode == 1) {
        y  = (unsigned short*)alloc(SZ_Y1);
        xb = (unsigned short*)alloc(SZ_Y1);
        t  = (unsigned short*)alloc(SZ_T);
    } else {
        y  = (unsigned short*)alloc(SZ_Y1);
        xb = nullptr;
        t  = (unsigned short*)alloc(SZ_T);
    }

    // zero the three contiguous int counter arrays (ws is poisoned 0xAA pre-call)
    hipMemsetAsync(cnt_out, 0, (size_t)((char*)cursor - (char*)cnt_out) + (size_t)NG * NN * 4, stream);

    k_count<<<(NG * NE + 255) / 256, 256, 0, stream>>>(e0, e1, e2, cnt_out, cnt_in);
    k_rs<<<(NG * NN + 255) / 256, 256, 0, stream>>>(cnt_out, cnt_in, rs_out, rs_in);
    k_scan<<<NG, 1024, 0, stream>>>(cnt_in, row_off);
    k_fill<<<(NG * NE + 255) / 256, 256, 0, stream>>>(e0, e1, e2, row_off, cursor, csr);
    k_misc<<<(NG * KHID + 255) / 256, 256, 0, stream>>>(alphas, b0, b1, b2, aptr, bcat);
    k_wt<<<NG * 256 + 384, 256, 0, stream>>>(W0, W1, W2, Wlin, Wt, Wlt);

    if (mode >= 1) {
        k_xbf<<<NN * KIN / (256 * 8), 256, 0, stream>>>(x, xb);
    }

    if (mode == 2) {
        k_agg_bf<<<dim3(NN / 4, 1, NG), 256, 0, stream>>>(
            xb, csr, row_off, rs_out, rs_in, y, (size_t)NN * KIN, 0);
        k_gemm<KIN, 128, true><<<dim3(MTILES, KHID / 128, NG), 256, 0, stream>>>(
            y, (size_t)NN * KIN, Wt, bcat, aptr, 0, t, nullptr);
    } else {
        for (int g = 0; g < NG; g++) {
            if (mode == 1)
                k_agg_bf<<<dim3(NN / 4, 1, 1), 256, 0, stream>>>(
                    xb, csr, row_off, rs_out, rs_in, y, 0, g);
            else
                k_agg_f32<<<NN / 4, 256, 0, stream>>>(x, csr, row_off, rs_out, rs_in, y, g);
            k_gemm<KIN, 128, true><<<dim3(MTILES, KHID / 128, 1), 256, 0, stream>>>(
                y, 0, Wt, bcat, aptr, g, t, nullptr);
        }
    }
    k_gemm<KCAT, 64, false><<<dim3(MTILES, KOUT / 64, 1), 256, 0, stream>>>(
        t, 0, Wlt, blin, nullptr, 0, nullptr, out);
}

// Round 3
// 425.672 us; speedup vs baseline: 1.2781x; 1.1260x over previous
//
#include <hip/hip_runtime.h>

#define NN 30000      // nodes
#define NE 150000     // edges per graph
#define KIN 512
#define KHID 512
#define KOUT 256
#define NG 3
#define KCAT (KHID*NG)   // 1536
#define MTILES ((NN + 127) / 128)   // 235
#define NCHUNK 30            // ceil(NN/1024)

typedef __attribute__((ext_vector_type(8))) __bf16 bf16x8;
typedef __attribute__((ext_vector_type(4))) float  f32x4;
typedef __attribute__((ext_vector_type(8))) unsigned short u16x8;

__device__ __forceinline__ unsigned short f2bf(float f) {
    unsigned u = __float_as_uint(f);
    u = (u + 0x7FFFu + ((u >> 16) & 1u)) >> 16;   // round-to-nearest-even
    return (unsigned short)u;
}
__device__ __forceinline__ float bf2f(unsigned short u) {
    return __uint_as_float((unsigned)u << 16);
}
__device__ __forceinline__ float fast_tanh(float x) {
    // tanh(x) = 1 - 2/(e^{2x}+1); v_exp + v_rcp, err ~1e-6 << bf16 quantum
    float e = __expf(2.f * x);
    return 1.f - __fdividef(2.f, e + 1.f);
}
__device__ __forceinline__ void gl_lds16(const void* g, void* l) {
    __builtin_amdgcn_global_load_lds(
        (const __attribute__((address_space(1))) void*)g,
        (__attribute__((address_space(3))) void*)l, 16, 0, 0);
}

// ---------- degree histogram ----------
__global__ void k_count(const int* __restrict__ e0, const int* __restrict__ e1,
                        const int* __restrict__ e2, int* cnt_out, int* cnt_in) {
    int idx = blockIdx.x * 256 + threadIdx.x;
    if (idx >= NG * NE) return;
    int g = idx / NE, e = idx - g * NE;
    const int* ed = (g == 0) ? e0 : ((g == 1) ? e1 : e2);
    atomicAdd(&cnt_out[g * NN + ed[e]], 1);        // src row
    atomicAdd(&cnt_in [g * NN + ed[NE + e]], 1);   // dst row
}

// ---------- rsqrt(clip(deg,1)) ----------
__global__ void k_rs(const int* cnt_out, const int* cnt_in, float* rs_out, float* rs_in) {
    int idx = blockIdx.x * 256 + threadIdx.x;
    if (idx >= NG * NN) return;
    int co = cnt_out[idx]; if (co < 1) co = 1;
    int ci = cnt_in [idx]; if (ci < 1) ci = 1;
    rs_out[idx] = rsqrtf((float)co);
    rs_in [idx] = rsqrtf((float)ci);
}

// ---------- parallel scan, phase 1: per-1024-chunk sums ----------
__global__ __launch_bounds__(256) void k_scan1(const int* __restrict__ cnt_in,
                                               int* __restrict__ csum) {
    int g = blockIdx.y, c = blockIdx.x;
    const int* cc = cnt_in + g * NN;
    int i = c * 1024 + threadIdx.x * 4;
    int4 v = {0, 0, 0, 0};
    if (i + 3 < NN) v = *(const int4*)(cc + i);
    else {
        if (i     < NN) v.x = cc[i];
        if (i + 1 < NN) v.y = cc[i + 1];
        if (i + 2 < NN) v.z = cc[i + 2];
        if (i + 3 < NN) v.w = cc[i + 3];
    }
    int s = v.x + v.y + v.z + v.w;
    #pragma unroll
    for (int o = 32; o > 0; o >>= 1) s += __shfl_down(s, o, 64);
    __shared__ int ws[4];
    if ((threadIdx.x & 63) == 0) ws[threadIdx.x >> 6] = s;
    __syncthreads();
    if (threadIdx.x == 0) csum[g * 32 + c] = ws[0] + ws[1] + ws[2] + ws[3];
}

// ---------- phase 2: exclusive scan of the 30 chunk sums (one wave per graph) ----------
__global__ void k_scan2(int* __restrict__ csum) {
    int g = threadIdx.x >> 6, lane = threadIdx.x & 63;
    if (g >= NG) return;
    int v = (lane < NCHUNK) ? csum[g * 32 + lane] : 0;
    int inc = v;
    #pragma unroll
    for (int o = 1; o < 32; o <<= 1) {
        int n = __shfl_up(inc, o, 64);
        if (lane >= o) inc += n;
    }
    if (lane < NCHUNK) csum[g * 32 + lane] = inc - v;   // exclusive base
}

// ---------- phase 3: in-chunk scan + base -> row_off ----------
__global__ __launch_bounds__(256) void k_scan3(const int* __restrict__ cnt_in,
        const int* __restrict__ csum, int* __restrict__ row_off) {
    int g = blockIdx.y, c = blockIdx.x;
    const int* cc = cnt_in + g * NN;
    int* ro = row_off + g * (NN + 1);
    int tid = threadIdx.x, lane = tid & 63, w = tid >> 6;
    int i = c * 1024 + tid * 4;
    int4 v = {0, 0, 0, 0};
    if (i + 3 < NN) v = *(const int4*)(cc + i);
    else {
        if (i     < NN) v.x = cc[i];
        if (i + 1 < NN) v.y = cc[i + 1];
        if (i + 2 < NN) v.z = cc[i + 2];
        if (i + 3 < NN) v.w = cc[i + 3];
    }
    int s = v.x + v.y + v.z + v.w;
    int inc = s;
    #pragma unroll
    for (int o = 1; o < 64; o <<= 1) {
        int n = __shfl_up(inc, o, 64);
        if (lane >= o) inc += n;
    }
    __shared__ int ws[4];
    if (lane == 63) ws[w] = inc;
    __syncthreads();
    int base = csum[g * 32 + c];
    for (int k = 0; k < w; k++) base += ws[k];
    int excl = base + inc - s;
    if (i     < NN) ro[i]     = excl;
    if (i + 1 < NN) ro[i + 1] = excl + v.x;
    if (i + 2 < NN) ro[i + 2] = excl + v.x + v.y;
    if (i + 3 < NN) ro[i + 3] = excl + v.x + v.y + v.z;
    if (c == 0 && tid == 0) ro[NN] = NE;   // total edges per graph is always NE
}

// ---------- CSR fill ----------
__global__ void k_fill(const int* __restrict__ e0, const int* __restrict__ e1,
                       const int* __restrict__ e2, const int* __restrict__ row_off,
                       int* cursor, int* __restrict__ csr) {
    int idx = blockIdx.x * 256 + threadIdx.x;
    if (idx >= NG * NE) return;
    int g = idx / NE, e = idx - g * NE;
    const int* ed = (g == 0) ? e0 : ((g == 1) ? e1 : e2);
    int s = ed[e], d = ed[NE + e];
    int pos = atomicAdd(&cursor[g * NN + d], 1);
    csr[g * NE + row_off[g * (NN + 1) + d] + pos] = s;
}

// ---------- softmax(alphas) + pack branch biases contiguous ----------
__global__ void k_misc(const float* __restrict__ alphas,
                       const float* __restrict__ b0, const float* __restrict__ b1,
                       const float* __restrict__ b2, float* __restrict__ aptr,
                       float* __restrict__ bcat) {
    int idx = blockIdx.x * 256 + threadIdx.x;
    if (idx < NG * KHID) {
        int g = idx >> 9;
        const float* b = (g == 0) ? b0 : ((g == 1) ? b1 : b2);
        bcat[idx] = b[idx & 511];
    }
    if (idx == 0) {
        float m = fmaxf(alphas[0], fmaxf(alphas[1], alphas[2]));
        float ex0 = expf(alphas[0] - m), ex1 = expf(alphas[1] - m), ex2 = expf(alphas[2] - m);
        float s = ex0 + ex1 + ex2;
        aptr[0] = ex0 / s; aptr[1] = ex1 / s; aptr[2] = ex2 / s;
    }
}

// ---------- weights -> bf16 transposed [n][k], coalesced via 32x32 LDS tile ----------
__global__ __launch_bounds__(256) void k_wt(const float* __restrict__ W0,
        const float* __restrict__ W1, const float* __restrict__ W2,
        const float* __restrict__ Wlin,
        unsigned short* __restrict__ Wt, unsigned short* __restrict__ Wlt) {
    __shared__ float Ls[32][33];
    int bid = blockIdx.x;
    const float* src; unsigned short* dst; int ncols, kdim, k0, n0;
    if (bid < NG * 256) {
        int g = bid >> 8, t = bid & 255;
        int kt = t >> 4, nt = t & 15;
        src = (g == 0) ? W0 : ((g == 1) ? W1 : W2);
        dst = Wt + (size_t)g * KIN * KHID;
        ncols = KHID; kdim = KIN; k0 = kt * 32; n0 = nt * 32;
    } else {
        int t = bid - NG * 256;
        int kt = t % 48, nt = t / 48;
        src = Wlin; dst = Wlt; ncols = KOUT; kdim = KCAT; k0 = kt * 32; n0 = nt * 32;
    }
    int tid = threadIdx.x;
    int r = tid >> 3, c4 = (tid & 7) * 4;
    float4 v = *(const float4*)(src + (size_t)(k0 + r) * ncols + n0 + c4);
    Ls[r][c4 + 0] = v.x; Ls[r][c4 + 1] = v.y; Ls[r][c4 + 2] = v.z; Ls[r][c4 + 3] = v.w;
    __syncthreads();
    int nr = tid >> 3, kc = (tid & 7) * 4;
    ushort4 o;
    o.x = f2bf(Ls[kc + 0][nr]); o.y = f2bf(Ls[kc + 1][nr]);
    o.z = f2bf(Ls[kc + 2][nr]); o.w = f2bf(Ls[kc + 3][nr]);
    *(ushort4*)(dst + (size_t)(n0 + nr) * kdim + k0 + kc) = o;
}

// ---------- x -> bf16 ----------
__global__ void k_xbf(const float* __restrict__ x, unsigned short* __restrict__ xb) {
    size_t i = ((size_t)blockIdx.x * 256 + threadIdx.x) * 8;
    float4 v0 = *(const float4*)(x + i);
    float4 v1 = *(const float4*)(x + i + 4);
    uint4 pk;
    pk.x = (unsigned)f2bf(v0.x) | ((unsigned)f2bf(v0.y) << 16);
    pk.y = (unsigned)f2bf(v0.z) | ((unsigned)f2bf(v0.w) << 16);
    pk.z = (unsigned)f2bf(v1.x) | ((unsigned)f2bf(v1.y) << 16);
    pk.w = (unsigned)f2bf(v1.z) | ((unsigned)f2bf(v1.w) << 16);
    *(uint4*)(xb + i) = pk;
}

// ---------- aggregation (bf16 x), 2-way unrolled gather ----------
__global__ __launch_bounds__(256) void k_agg_bf(const unsigned short* __restrict__ xb,
        const int* __restrict__ csr, const int* __restrict__ row_off,
        const float* __restrict__ rs_out, const float* __restrict__ rs_in,
        unsigned short* __restrict__ y, size_t ystride, int gbase) {
    int g    = gbase + blockIdx.z;
    int d    = blockIdx.x * 4 + (threadIdx.x >> 6);
    int lane = threadIdx.x & 63;
    int beg = row_off[g * (NN + 1) + d];
    int end = row_off[g * (NN + 1) + d + 1];
    const int* cs = csr + g * NE;
    const float* rso = rs_out + g * NN;
    float a0=0,a1=0,a2=0,a3=0,a4=0,a5=0,a6=0,a7=0;
    const unsigned short* xbl = xb + lane * 8;
    int e = beg;
    for (; e + 1 < end; e += 2) {       // two independent gather chains
        int s0 = cs[e], s1 = cs[e + 1];
        float w0 = rso[s0], w1 = rso[s1];
        u16x8 v0 = *(const u16x8*)(xbl + (size_t)s0 * KIN);
        u16x8 v1 = *(const u16x8*)(xbl + (size_t)s1 * KIN);
        a0 += w0 * bf2f(v0[0]) + w1 * bf2f(v1[0]);
        a1 += w0 * bf2f(v0[1]) + w1 * bf2f(v1[1]);
        a2 += w0 * bf2f(v0[2]) + w1 * bf2f(v1[2]);
        a3 += w0 * bf2f(v0[3]) + w1 * bf2f(v1[3]);
        a4 += w0 * bf2f(v0[4]) + w1 * bf2f(v1[4]);
        a5 += w0 * bf2f(v0[5]) + w1 * bf2f(v1[5]);
        a6 += w0 * bf2f(v0[6]) + w1 * bf2f(v1[6]);
        a7 += w0 * bf2f(v0[7]) + w1 * bf2f(v1[7]);
    }
    if (e < end) {
        int s0 = cs[e];
        float w0 = rso[s0];
        u16x8 v0 = *(const u16x8*)(xbl + (size_t)s0 * KIN);
        a0 += w0 * bf2f(v0[0]); a1 += w0 * bf2f(v0[1]);
        a2 += w0 * bf2f(v0[2]); a3 += w0 * bf2f(v0[3]);
        a4 += w0 * bf2f(v0[4]); a5 += w0 * bf2f(v0[5]);
        a6 += w0 * bf2f(v0[6]); a7 += w0 * bf2f(v0[7]);
    }
    float ri = rs_in[g * NN + d];
    uint4 pk;
    pk.x = (unsigned)f2bf(a0 * ri) | ((unsigned)f2bf(a1 * ri) << 16);
    pk.y = (unsigned)f2bf(a2 * ri) | ((unsigned)f2bf(a3 * ri) << 16);
    pk.z = (unsigned)f2bf(a4 * ri) | ((unsigned)f2bf(a5 * ri) << 16);
    pk.w = (unsigned)f2bf(a6 * ri) | ((unsigned)f2bf(a7 * ri) << 16);
    *(uint4*)(y + (size_t)g * ystride + (size_t)d * KIN + lane * 8) = pk;
}

// ---------- aggregation (fp32 x fallback) ----------
__global__ __launch_bounds__(256) void k_agg_f32(const float* __restrict__ x,
        const int* __restrict__ csr, const int* __restrict__ row_off,
        const float* __restrict__ rs_out, const float* __restrict__ rs_in,
        unsigned short* __restrict__ y, int g) {
    int d    = blockIdx.x * 4 + (threadIdx.x >> 6);
    int lane = threadIdx.x & 63;
    int beg = row_off[g * (NN + 1) + d];
    int end = row_off[g * (NN + 1) + d + 1];
    const int* cs = csr + g * NE;
    float a0=0,a1=0,a2=0,a3=0,a4=0,a5=0,a6=0,a7=0;
    const float* xb = x + lane * 8;
    for (int e = beg; e < end; e++) {
        int s = cs[e];
        float wsc = rs_out[g * NN + s];
        const float4* xr = (const float4*)(xb + (size_t)s * KIN);
        float4 v0 = xr[0], v1 = xr[1];
        a0 += wsc * v0.x; a1 += wsc * v0.y; a2 += wsc * v0.z; a3 += wsc * v0.w;
        a4 += wsc * v1.x; a5 += wsc * v1.y; a6 += wsc * v1.z; a7 += wsc * v1.w;
    }
    float ri = rs_in[g * NN + d];
    uint4 pk;
    pk.x = (unsigned)f2bf(a0 * ri) | ((unsigned)f2bf(a1 * ri) << 16);
    pk.y = (unsigned)f2bf(a2 * ri) | ((unsigned)f2bf(a3 * ri) << 16);
    pk.z = (unsigned)f2bf(a4 * ri) | ((unsigned)f2bf(a5 * ri) << 16);
    pk.w = (unsigned)f2bf(a6 * ri) | ((unsigned)f2bf(a7 * ri) << 16);
    *(uint4*)(y + (size_t)d * KIN + lane * 8) = pk;
}

// ---------- 128xNT bf16 MFMA GEMM, double-buffered LDS (1 barrier/iter) ----------
template<int KDIM, int NT, bool TANH>
__global__ __launch_bounds__(256) void k_gemm(const unsigned short* __restrict__ A,
        size_t agstride, const unsigned short* __restrict__ Bt,
        const float* __restrict__ bias, const float* __restrict__ aptr, int gbase,
        unsigned short* __restrict__ Tout, float* __restrict__ Fout) {
    constexpr int NF = NT / 32;
    constexpr int NITER = KDIM / 32;
    __shared__ __align__(16) unsigned short As[2][128 * 32];
    __shared__ __align__(16) unsigned short Bs[2][NT * 32];
    int g = gbase + blockIdx.z;
    const unsigned short* Ab = A + (size_t)g * agstride;
    const unsigned short* Bb = TANH ? (Bt + (size_t)g * KIN * KHID) : Bt;
    const float* bb = TANH ? (bias + g * KHID) : bias;
    int m0 = blockIdx.x * 128;
    int n0 = blockIdx.y * NT;
    int tid = threadIdx.x, lane = tid & 63, w = tid >> 6;

    f32x4 acc[4][NF];
    #pragma unroll
    for (int i = 0; i < 4; i++)
        #pragma unroll
        for (int j = 0; j < NF; j++) acc[i][j] = (f32x4){0.f, 0.f, 0.f, 0.f};

    int mbase = (w & 1) * 64;
    int nbase = (w >> 1) * (NT / 2);
    int mf = mbase + (lane & 15);
    int nf = nbase + (lane & 15);
    int kq = (lane >> 4) * 8;

    int ar0 = tid >> 2, ak0 = (tid & 3) * 8;
    int ga0 = m0 + ar0;      if (ga0 >= NN) ga0 = NN - 1;
    int ga1 = m0 + ar0 + 64; if (ga1 >= NN) ga1 = NN - 1;
    const unsigned short* Ag0 = Ab + (size_t)ga0 * KDIM + ak0;
    const unsigned short* Ag1 = Ab + (size_t)ga1 * KDIM + ak0;
    const unsigned short* Bg0 = Bb + (size_t)(n0 + ar0) * KDIM + ak0;
    const unsigned short* Bg1 = Bb + (size_t)(n0 + ar0 + 64) * KDIM + ak0;

    auto stage = [&](int buf, int k0) {
        gl_lds16(Ag0 + k0, &As[buf][tid * 8]);
        gl_lds16(Ag1 + k0, &As[buf][(tid + 256) * 8]);
        gl_lds16(Bg0 + k0, &Bs[buf][tid * 8]);
        if constexpr (NT == 128) gl_lds16(Bg1 + k0, &Bs[buf][(tid + 256) * 8]);
    };
    stage(0, 0);
    for (int it = 0; it < NITER; it++) {
        __syncthreads();                       // drains prev stage (vmcnt) + prev reads
        if (it + 1 < NITER) stage((it + 1) & 1, (it + 1) * 32);
        const unsigned short* Al = As[it & 1];
        const unsigned short* Bl = Bs[it & 1];
        bf16x8 af[4], bfr[NF];
        #pragma unroll
        for (int mi = 0; mi < 4; mi++) af[mi] = *(const bf16x8*)&Al[(mf + mi * 16) * 32 + kq];
        #pragma unroll
        for (int ni = 0; ni < NF; ni++) bfr[ni] = *(const bf16x8*)&Bl[(nf + ni * 16) * 32 + kq];
        #pragma unroll
        for (int mi = 0; mi < 4; mi++)
            #pragma unroll
            for (int ni = 0; ni < NF; ni++)
                acc[mi][ni] = __builtin_amdgcn_mfma_f32_16x16x32_bf16(af[mi], bfr[ni], acc[mi][ni], 0, 0, 0);
    }

    float ascale = TANH ? aptr[g] : 0.f;
    int rb = mbase + (lane >> 4) * 4;
    #pragma unroll
    for (int mi = 0; mi < 4; mi++) {
        #pragma unroll
        for (int r = 0; r < 4; r++) {
            int row = m0 + rb + mi * 16 + r;
            if (row < NN) {
                #pragma unroll
                for (int ni = 0; ni < NF; ni++) {
                    int col = n0 + nbase + ni * 16 + (lane & 15);
                    float v = acc[mi][ni][r] + bb[col];
                    if (TANH) {
                        Tout[(size_t)row * KCAT + g * KHID + col] = f2bf(fast_tanh(ascale * v));
                    } else {
                        Fout[(size_t)row * KOUT + col] = v;
                    }
                }
            }
        }
    }
}

extern "C" void kernel_launch(void* const* d_in, const int* in_sizes, int n_in,
                              void* d_out, int out_size, void* d_ws, size_t ws_size,
                              hipStream_t stream) {
    const float* x      = (const float*)d_in[0];
    const int*   e0     = (const int*)  d_in[1];
    const float* W0     = (const float*)d_in[2];
    const float* b0     = (const float*)d_in[3];
    const int*   e1     = (const int*)  d_in[4];
    const float* W1     = (const float*)d_in[5];
    const float* b1     = (const float*)d_in[6];
    const int*   e2     = (const int*)  d_in[7];
    const float* W2     = (const float*)d_in[8];
    const float* b2     = (const float*)d_in[9];
    const float* alphas = (const float*)d_in[10];
    const float* Wlin   = (const float*)d_in[11];
    const float* blin   = (const float*)d_in[12];
    float* out = (float*)d_out;

    char* ws = (char*)d_ws;
    size_t off = 0;
    auto alloc = [&](size_t bytes) -> void* {
        void* p = ws + off;
        off = (off + bytes + 255) & ~(size_t)255;
        return p;
    };
    int*   cnt_out = (int*)  alloc((size_t)NG * NN * 4);
    int*   cnt_in  = (int*)  alloc((size_t)NG * NN * 4);
    int*   cursor  = (int*)  alloc((size_t)NG * NN * 4);
    int*   row_off = (int*)  alloc((size_t)NG * (NN + 1) * 4);
    int*   csr     = (int*)  alloc((size_t)NG * NE * 4);
    int*   csum    = (int*)  alloc((size_t)NG * 32 * 4);
    float* rs_out  = (float*)alloc((size_t)NG * NN * 4);
    float* rs_in   = (float*)alloc((size_t)NG * NN * 4);
    float* aptr    = (float*)alloc(16);
    float* bcat    = (float*)alloc((size_t)NG * KHID * 4);
    unsigned short* Wt  = (unsigned short*)alloc((size_t)NG * KIN * KHID * 2);
    unsigned short* Wlt = (unsigned short*)alloc((size_t)KCAT * KOUT * 2);

    const size_t SZ_Y1 = (size_t)NN * KIN * 2;     // 30.72 MB
    const size_t SZ_T  = (size_t)NN * KCAT * 2;    // 92.16 MB
    size_t remaining = (ws_size > off) ? (ws_size - off) : 0;
    int mode;                                       // 2=batched(bf16 agg), 1=loop(bf16 agg), 0=loop(f32 agg)
    if      (remaining >= 3 * SZ_Y1 + SZ_T + 8192)          mode = 2;  // xb aliases t
    else if (remaining >= SZ_Y1 + SZ_Y1 + SZ_T + 8192)      mode = 1;
    else                                                    mode = 0;

    unsigned short *y, *xb, *t;
    if (mode == 2) {
        y  = (unsigned short*)alloc(3 * SZ_Y1);
        t  = (unsigned short*)alloc(SZ_T);
        xb = t;                                    // xb dead before t is written
    } else if (mode == 1) {
        y  = (unsigned short*)alloc(SZ_Y1);
        xb = (unsigned short*)alloc(SZ_Y1);
        t  = (unsigned short*)alloc(SZ_T);
    } else {
        y  = (unsigned short*)alloc(SZ_Y1);
        xb = nullptr;
        t  = (unsigned short*)alloc(SZ_T);
    }

    // zero the three contiguous int counter arrays (ws is poisoned 0xAA pre-call)
    hipMemsetAsync(cnt_out, 0, (size_t)((char*)cursor - (char*)cnt_out) + (size_t)NG * NN * 4, stream);

    k_count<<<(NG * NE + 255) / 256, 256, 0, stream>>>(e0, e1, e2, cnt_out, cnt_in);
    k_rs<<<(NG * NN + 255) / 256, 256, 0, stream>>>(cnt_out, cnt_in, rs_out, rs_in);
    k_scan1<<<dim3(NCHUNK, NG), 256, 0, stream>>>(cnt_in, csum);
    k_scan2<<<1, 192, 0, stream>>>(csum);
    k_scan3<<<dim3(NCHUNK, NG), 256, 0, stream>>>(cnt_in, csum, row_off);
    k_fill<<<(NG * NE + 255) / 256, 256, 0, stream>>>(e0, e1, e2, row_off, cursor, csr);
    k_misc<<<(NG * KHID + 255) / 256, 256, 0, stream>>>(alphas, b0, b1, b2, aptr, bcat);
    k_wt<<<NG * 256 + 384, 256, 0, stream>>>(W0, W1, W2, Wlin, Wt, Wlt);

    if (mode >= 1) {
        k_xbf<<<NN * KIN / (256 * 8), 256, 0, stream>>>(x, xb);
    }

    if (mode == 2) {
        k_agg_bf<<<dim3(NN / 4, 1, NG), 256, 0, stream>>>(
            xb, csr, row_off, rs_out, rs_in, y, (size_t)NN * KIN, 0);
        k_gemm<KIN, 128, true><<<dim3(MTILES, KHID / 128, NG), 256, 0, stream>>>(
            y, (size_t)NN * KIN, Wt, bcat, aptr, 0, t, nullptr);
    } else {
        for (int g = 0; g < NG; g++) {
            if (mode == 1)
                k_agg_bf<<<dim3(NN / 4, 1, 1), 256, 0, stream>>>(
                    xb, csr, row_off, rs_out, rs_in, y, 0, g);
            else
                k_agg_f32<<<NN / 4, 256, 0, stream>>>(x, csr, row_off, rs_out, rs_in, y, g);
            k_gemm<KIN, 128, true><<<dim3(MTILES, KHID / 128, 1), 256, 0, stream>>>(
                y, 0, Wt, bcat, aptr, g, t, nullptr);
        }
    }
    k_gemm<KCAT, 64, false><<<dim3(MTILES, KOUT / 64, 1), 256, 0, stream>>>(
        t, 0, Wlt, blin, nullptr, 0, nullptr, out);
}

// Round 4
// 421.996 us; speedup vs baseline: 1.2892x; 1.0087x over previous
//
#include <hip/hip_runtime.h>

#define NN 30000      // nodes
#define NE 150000     // edges per graph
#define KIN 512
#define KHID 512
#define KOUT 256
#define NG 3
#define KCAT (KHID*NG)   // 1536
#define MTILES ((NN + 127) / 128)   // 235
#define NCHUNK 30            // ceil(NN/1024)

typedef __attribute__((ext_vector_type(8))) __bf16 bf16x8;
typedef __attribute__((ext_vector_type(4))) float  f32x4;
typedef __attribute__((ext_vector_type(8))) unsigned short u16x8;

__device__ __forceinline__ unsigned short f2bf(float f) {
    unsigned u = __float_as_uint(f);
    u = (u + 0x7FFFu + ((u >> 16) & 1u)) >> 16;   // round-to-nearest-even
    return (unsigned short)u;
}
__device__ __forceinline__ float bf2f(unsigned short u) {
    return __uint_as_float((unsigned)u << 16);
}
__device__ __forceinline__ float fast_tanh(float x) {
    float e = __expf(2.f * x);
    return 1.f - __fdividef(2.f, e + 1.f);
}
__device__ __forceinline__ void gl_lds16(const void* g, void* l) {
    __builtin_amdgcn_global_load_lds(
        (const __attribute__((address_space(1))) void*)g,
        (__attribute__((address_space(3))) void*)l, 16, 0, 0);
}

// ---------- degree histogram ----------
__global__ void k_count(const int* __restrict__ e0, const int* __restrict__ e1,
                        const int* __restrict__ e2, int* cnt_out, int* cnt_in) {
    int idx = blockIdx.x * 256 + threadIdx.x;
    if (idx >= NG * NE) return;
    int g = idx / NE, e = idx - g * NE;
    const int* ed = (g == 0) ? e0 : ((g == 1) ? e1 : e2);
    atomicAdd(&cnt_out[g * NN + ed[e]], 1);
    atomicAdd(&cnt_in [g * NN + ed[NE + e]], 1);
}

// ---------- rsqrt(clip(deg,1)) ----------
__global__ void k_rs(const int* cnt_out, const int* cnt_in, float* rs_out, float* rs_in) {
    int idx = blockIdx.x * 256 + threadIdx.x;
    if (idx >= NG * NN) return;
    int co = cnt_out[idx]; if (co < 1) co = 1;
    int ci = cnt_in [idx]; if (ci < 1) ci = 1;
    rs_out[idx] = rsqrtf((float)co);
    rs_in [idx] = rsqrtf((float)ci);
}

// ---------- parallel scan, phase 1: per-1024-chunk sums ----------
__global__ __launch_bounds__(256) void k_scan1(const int* __restrict__ cnt_in,
                                               int* __restrict__ csum) {
    int g = blockIdx.y, c = blockIdx.x;
    const int* cc = cnt_in + g * NN;
    int i = c * 1024 + threadIdx.x * 4;
    int4 v = {0, 0, 0, 0};
    if (i + 3 < NN) v = *(const int4*)(cc + i);
    else {
        if (i     < NN) v.x = cc[i];
        if (i + 1 < NN) v.y = cc[i + 1];
        if (i + 2 < NN) v.z = cc[i + 2];
        if (i + 3 < NN) v.w = cc[i + 3];
    }
    int s = v.x + v.y + v.z + v.w;
    #pragma unroll
    for (int o = 32; o > 0; o >>= 1) s += __shfl_down(s, o, 64);
    __shared__ int ws[4];
    if ((threadIdx.x & 63) == 0) ws[threadIdx.x >> 6] = s;
    __syncthreads();
    if (threadIdx.x == 0) csum[g * 32 + c] = ws[0] + ws[1] + ws[2] + ws[3];
}

// ---------- phase 2: exclusive scan of the 30 chunk sums (one wave per graph) ----------
__global__ void k_scan2(int* __restrict__ csum) {
    int g = threadIdx.x >> 6, lane = threadIdx.x & 63;
    if (g >= NG) return;
    int v = (lane < NCHUNK) ? csum[g * 32 + lane] : 0;
    int inc = v;
    #pragma unroll
    for (int o = 1; o < 32; o <<= 1) {
        int n = __shfl_up(inc, o, 64);
        if (lane >= o) inc += n;
    }
    if (lane < NCHUNK) csum[g * 32 + lane] = inc - v;
}

// ---------- phase 3: in-chunk scan + base -> row_off ----------
__global__ __launch_bounds__(256) void k_scan3(const int* __restrict__ cnt_in,
        const int* __restrict__ csum, int* __restrict__ row_off) {
    int g = blockIdx.y, c = blockIdx.x;
    const int* cc = cnt_in + g * NN;
    int* ro = row_off + g * (NN + 1);
    int tid = threadIdx.x, lane = tid & 63, w = tid >> 6;
    int i = c * 1024 + tid * 4;
    int4 v = {0, 0, 0, 0};
    if (i + 3 < NN) v = *(const int4*)(cc + i);
    else {
        if (i     < NN) v.x = cc[i];
        if (i + 1 < NN) v.y = cc[i + 1];
        if (i + 2 < NN) v.z = cc[i + 2];
        if (i + 3 < NN) v.w = cc[i + 3];
    }
    int s = v.x + v.y + v.z + v.w;
    int inc = s;
    #pragma unroll
    for (int o = 1; o < 64; o <<= 1) {
        int n = __shfl_up(inc, o, 64);
        if (lane >= o) inc += n;
    }
    __shared__ int ws[4];
    if (lane == 63) ws[w] = inc;
    __syncthreads();
    int base = csum[g * 32 + c];
    for (int k = 0; k < w; k++) base += ws[k];
    int excl = base + inc - s;
    if (i     < NN) ro[i]     = excl;
    if (i + 1 < NN) ro[i + 1] = excl + v.x;
    if (i + 2 < NN) ro[i + 2] = excl + v.x + v.y;
    if (i + 3 < NN) ro[i + 3] = excl + v.x + v.y + v.z;
    if (c == 0 && tid == 0) ro[NN] = NE;
}

// ---------- CSR fill ----------
__global__ void k_fill(const int* __restrict__ e0, const int* __restrict__ e1,
                       const int* __restrict__ e2, const int* __restrict__ row_off,
                       int* cursor, int* __restrict__ csr) {
    int idx = blockIdx.x * 256 + threadIdx.x;
    if (idx >= NG * NE) return;
    int g = idx / NE, e = idx - g * NE;
    const int* ed = (g == 0) ? e0 : ((g == 1) ? e1 : e2);
    int s = ed[e], d = ed[NE + e];
    int pos = atomicAdd(&cursor[g * NN + d], 1);
    csr[g * NE + row_off[g * (NN + 1) + d] + pos] = s;
}

// ---------- softmax(alphas) + pack branch biases contiguous ----------
__global__ void k_misc(const float* __restrict__ alphas,
                       const float* __restrict__ b0, const float* __restrict__ b1,
                       const float* __restrict__ b2, float* __restrict__ aptr,
                       float* __restrict__ bcat) {
    int idx = blockIdx.x * 256 + threadIdx.x;
    if (idx < NG * KHID) {
        int g = idx >> 9;
        const float* b = (g == 0) ? b0 : ((g == 1) ? b1 : b2);
        bcat[idx] = b[idx & 511];
    }
    if (idx == 0) {
        float m = fmaxf(alphas[0], fmaxf(alphas[1], alphas[2]));
        float ex0 = expf(alphas[0] - m), ex1 = expf(alphas[1] - m), ex2 = expf(alphas[2] - m);
        float s = ex0 + ex1 + ex2;
        aptr[0] = ex0 / s; aptr[1] = ex1 / s; aptr[2] = ex2 / s;
    }
}

// ---------- weights -> bf16 transposed [n][k], coalesced via 32x32 LDS tile ----------
__global__ __launch_bounds__(256) void k_wt(const float* __restrict__ W0,
        const float* __restrict__ W1, const float* __restrict__ W2,
        const float* __restrict__ Wlin,
        unsigned short* __restrict__ Wt, unsigned short* __restrict__ Wlt) {
    __shared__ float Ls[32][33];
    int bid = blockIdx.x;
    const float* src; unsigned short* dst; int ncols, kdim, k0, n0;
    if (bid < NG * 256) {
        int g = bid >> 8, t = bid & 255;
        int kt = t >> 4, nt = t & 15;
        src = (g == 0) ? W0 : ((g == 1) ? W1 : W2);
        dst = Wt + (size_t)g * KIN * KHID;
        ncols = KHID; kdim = KIN; k0 = kt * 32; n0 = nt * 32;
    } else {
        int t = bid - NG * 256;
        int kt = t % 48, nt = t / 48;
        src = Wlin; dst = Wlt; ncols = KOUT; kdim = KCAT; k0 = kt * 32; n0 = nt * 32;
    }
    int tid = threadIdx.x;
    int r = tid >> 3, c4 = (tid & 7) * 4;
    float4 v = *(const float4*)(src + (size_t)(k0 + r) * ncols + n0 + c4);
    Ls[r][c4 + 0] = v.x; Ls[r][c4 + 1] = v.y; Ls[r][c4 + 2] = v.z; Ls[r][c4 + 3] = v.w;
    __syncthreads();
    int nr = tid >> 3, kc = (tid & 7) * 4;
    ushort4 o;
    o.x = f2bf(Ls[kc + 0][nr]); o.y = f2bf(Ls[kc + 1][nr]);
    o.z = f2bf(Ls[kc + 2][nr]); o.w = f2bf(Ls[kc + 3][nr]);
    *(ushort4*)(dst + (size_t)(n0 + nr) * kdim + k0 + kc) = o;
}

// ---------- x -> bf16 ----------
__global__ void k_xbf(const float* __restrict__ x, unsigned short* __restrict__ xb) {
    size_t i = ((size_t)blockIdx.x * 256 + threadIdx.x) * 8;
    float4 v0 = *(const float4*)(x + i);
    float4 v1 = *(const float4*)(x + i + 4);
    uint4 pk;
    pk.x = (unsigned)f2bf(v0.x) | ((unsigned)f2bf(v0.y) << 16);
    pk.y = (unsigned)f2bf(v0.z) | ((unsigned)f2bf(v0.w) << 16);
    pk.z = (unsigned)f2bf(v1.x) | ((unsigned)f2bf(v1.y) << 16);
    pk.w = (unsigned)f2bf(v1.z) | ((unsigned)f2bf(v1.w) << 16);
    *(uint4*)(xb + i) = pk;
}

// ---------- aggregation (bf16 x), 2-way unrolled gather ----------
__global__ __launch_bounds__(256) void k_agg_bf(const unsigned short* __restrict__ xb,
        const int* __restrict__ csr, const int* __restrict__ row_off,
        const float* __restrict__ rs_out, const float* __restrict__ rs_in,
        unsigned short* __restrict__ y, size_t ystride, int gbase) {
    int g    = gbase + blockIdx.z;
    int d    = blockIdx.x * 4 + (threadIdx.x >> 6);
    int lane = threadIdx.x & 63;
    int beg = row_off[g * (NN + 1) + d];
    int end = row_off[g * (NN + 1) + d + 1];
    const int* cs = csr + g * NE;
    const float* rso = rs_out + g * NN;
    float a0=0,a1=0,a2=0,a3=0,a4=0,a5=0,a6=0,a7=0;
    const unsigned short* xbl = xb + lane * 8;
    int e = beg;
    for (; e + 1 < end; e += 2) {
        int s0 = cs[e], s1 = cs[e + 1];
        float w0 = rso[s0], w1 = rso[s1];
        u16x8 v0 = *(const u16x8*)(xbl + (size_t)s0 * KIN);
        u16x8 v1 = *(const u16x8*)(xbl + (size_t)s1 * KIN);
        a0 += w0 * bf2f(v0[0]) + w1 * bf2f(v1[0]);
        a1 += w0 * bf2f(v0[1]) + w1 * bf2f(v1[1]);
        a2 += w0 * bf2f(v0[2]) + w1 * bf2f(v1[2]);
        a3 += w0 * bf2f(v0[3]) + w1 * bf2f(v1[3]);
        a4 += w0 * bf2f(v0[4]) + w1 * bf2f(v1[4]);
        a5 += w0 * bf2f(v0[5]) + w1 * bf2f(v1[5]);
        a6 += w0 * bf2f(v0[6]) + w1 * bf2f(v1[6]);
        a7 += w0 * bf2f(v0[7]) + w1 * bf2f(v1[7]);
    }
    if (e < end) {
        int s0 = cs[e];
        float w0 = rso[s0];
        u16x8 v0 = *(const u16x8*)(xbl + (size_t)s0 * KIN);
        a0 += w0 * bf2f(v0[0]); a1 += w0 * bf2f(v0[1]);
        a2 += w0 * bf2f(v0[2]); a3 += w0 * bf2f(v0[3]);
        a4 += w0 * bf2f(v0[4]); a5 += w0 * bf2f(v0[5]);
        a6 += w0 * bf2f(v0[6]); a7 += w0 * bf2f(v0[7]);
    }
    float ri = rs_in[g * NN + d];
    uint4 pk;
    pk.x = (unsigned)f2bf(a0 * ri) | ((unsigned)f2bf(a1 * ri) << 16);
    pk.y = (unsigned)f2bf(a2 * ri) | ((unsigned)f2bf(a3 * ri) << 16);
    pk.z = (unsigned)f2bf(a4 * ri) | ((unsigned)f2bf(a5 * ri) << 16);
    pk.w = (unsigned)f2bf(a6 * ri) | ((unsigned)f2bf(a7 * ri) << 16);
    *(uint4*)(y + (size_t)g * ystride + (size_t)d * KIN + lane * 8) = pk;
}

// ---------- aggregation (fp32 x fallback) ----------
__global__ __launch_bounds__(256) void k_agg_f32(const float* __restrict__ x,
        const int* __restrict__ csr, const int* __restrict__ row_off,
        const float* __restrict__ rs_out, const float* __restrict__ rs_in,
        unsigned short* __restrict__ y, int g) {
    int d    = blockIdx.x * 4 + (threadIdx.x >> 6);
    int lane = threadIdx.x & 63;
    int beg = row_off[g * (NN + 1) + d];
    int end = row_off[g * (NN + 1) + d + 1];
    const int* cs = csr + g * NE;
    float a0=0,a1=0,a2=0,a3=0,a4=0,a5=0,a6=0,a7=0;
    const float* xb = x + lane * 8;
    for (int e = beg; e < end; e++) {
        int s = cs[e];
        float wsc = rs_out[g * NN + s];
        const float4* xr = (const float4*)(xb + (size_t)s * KIN);
        float4 v0 = xr[0], v1 = xr[1];
        a0 += wsc * v0.x; a1 += wsc * v0.y; a2 += wsc * v0.z; a3 += wsc * v0.w;
        a4 += wsc * v1.x; a5 += wsc * v1.y; a6 += wsc * v1.z; a7 += wsc * v1.w;
    }
    float ri = rs_in[g * NN + d];
    uint4 pk;
    pk.x = (unsigned)f2bf(a0 * ri) | ((unsigned)f2bf(a1 * ri) << 16);
    pk.y = (unsigned)f2bf(a2 * ri) | ((unsigned)f2bf(a3 * ri) << 16);
    pk.z = (unsigned)f2bf(a4 * ri) | ((unsigned)f2bf(a5 * ri) << 16);
    pk.w = (unsigned)f2bf(a6 * ri) | ((unsigned)f2bf(a7 * ri) << 16);
    *(uint4*)(y + (size_t)d * KIN + lane * 8) = pk;
}

// ---------- full-N MFMA GEMM: 128m x BN tile, wave tile 64x128, XOR-swizzled LDS ----------
// THREADS = BN (512 -> 8 waves, 256 -> 4 waves). Double-buffered, 1 barrier/iter.
// LDS chunk (row, j) holds global (row, j ^ ((row>>1)&3)) -- kills 8-way bank conflicts
// (row stride 64B = 16 banks aliases rows mod 2; swizzle spreads 16-lane phase over
//  8 bank-groups -> 2-way, which is free per m136).
template<int KDIM, int BN, bool TANH>
__global__ __launch_bounds__(BN, 2) void k_gemm(const unsigned short* __restrict__ A,
        size_t agstride, const unsigned short* __restrict__ Bt,
        const float* __restrict__ bias, const float* __restrict__ aptr, int gbase,
        unsigned short* __restrict__ Tout, float* __restrict__ Fout) {
    constexpr int THREADS = BN;
    constexpr int NITER = KDIM / 32;
    constexpr int ACH = 512 / THREADS;        // A chunks per thread (A = 128x4 chunks)
    constexpr int BCH = 4;                    // B chunks per thread (B = BN x 4 chunks)
    __shared__ __align__(16) unsigned short As[2][128 * 32];
    __shared__ __align__(16) unsigned short Bs[2][BN * 32];
    int g = gbase + blockIdx.z;
    const unsigned short* Ab = A + (size_t)g * agstride;
    const unsigned short* Bb = TANH ? (Bt + (size_t)g * KIN * KHID) : Bt;
    const float* bb = TANH ? (bias + g * KHID) : bias;
    int m0 = blockIdx.x * 128;
    int tid = threadIdx.x, lane = tid & 63, w = tid >> 6;
    int mq = w & 1, nq = w >> 1;              // wave = 64m x 128n subtile

    f32x4 acc[4][8];
    #pragma unroll
    for (int i = 0; i < 4; i++)
        #pragma unroll
        for (int j = 0; j < 8; j++) acc[i][j] = (f32x4){0.f, 0.f, 0.f, 0.f};

    // staging source pointers (global), XOR-swizzled chunk column
    const unsigned short* Ag[ACH];
    unsigned short* Al[ACH];
    #pragma unroll
    for (int j = 0; j < ACH; j++) {
        int c = tid + THREADS * j;
        int r = c >> 2, q = (c & 3) ^ ((c >> 3) & 3);
        int grow = m0 + r; if (grow >= NN) grow = NN - 1;
        Ag[j] = Ab + (size_t)grow * KDIM + q * 8;
        Al[j] = (unsigned short*)&As[0][c * 8];
    }
    const unsigned short* Bg[BCH];
    unsigned short* Bl[BCH];
    #pragma unroll
    for (int j = 0; j < BCH; j++) {
        int c = tid + THREADS * j;
        int r = c >> 2, q = (c & 3) ^ ((c >> 3) & 3);
        Bg[j] = Bb + (size_t)r * KDIM + q * 8;
        Bl[j] = (unsigned short*)&Bs[0][c * 8];
    }
    constexpr int ABUF = 128 * 32, BBUF = BN * 32;

    auto stage = [&](int buf, int k0) {
        #pragma unroll
        for (int j = 0; j < ACH; j++) gl_lds16(Ag[j] + k0, Al[j] + buf * ABUF);
        #pragma unroll
        for (int j = 0; j < BCH; j++) gl_lds16(Bg[j] + k0, Bl[j] + buf * BBUF);
    };

    // fragment read offsets (element units); kqs folds the XOR swizzle (uniform over mi/ni)
    int kqs = (((lane >> 4) ^ ((lane >> 1) & 3))) * 8;
    int arow = mq * 64 + (lane & 15);
    int nrow = nq * 128 + (lane & 15);

    stage(0, 0);
    for (int it = 0; it < NITER; it++) {
        __syncthreads();
        if (it + 1 < NITER) stage((it + 1) & 1, (it + 1) * 32);
        const unsigned short* Alb = As[it & 1];
        const unsigned short* Blb = Bs[it & 1];
        bf16x8 af[4], bfr[8];
        #pragma unroll
        for (int mi = 0; mi < 4; mi++) af[mi] = *(const bf16x8*)&Alb[(arow + mi * 16) * 32 + kqs];
        #pragma unroll
        for (int ni = 0; ni < 8; ni++) bfr[ni] = *(const bf16x8*)&Blb[(nrow + ni * 16) * 32 + kqs];
        #pragma unroll
        for (int mi = 0; mi < 4; mi++)
            #pragma unroll
            for (int ni = 0; ni < 8; ni++)
                acc[mi][ni] = __builtin_amdgcn_mfma_f32_16x16x32_bf16(af[mi], bfr[ni], acc[mi][ni], 0, 0, 0);
    }

    float ascale = TANH ? aptr[g] : 0.f;
    int rb = mq * 64 + (lane >> 4) * 4;
    #pragma unroll
    for (int mi = 0; mi < 4; mi++) {
        #pragma unroll
        for (int r = 0; r < 4; r++) {
            int row = m0 + rb + mi * 16 + r;
            if (row < NN) {
                #pragma unroll
                for (int ni = 0; ni < 8; ni++) {
                    int col = nq * 128 + ni * 16 + (lane & 15);
                    float v = acc[mi][ni][r] + bb[col];
                    if (TANH) {
                        Tout[(size_t)row * KCAT + g * KHID + col] = f2bf(fast_tanh(ascale * v));
                    } else {
                        Fout[(size_t)row * KOUT + col] = v;
                    }
                }
            }
        }
    }
}

extern "C" void kernel_launch(void* const* d_in, const int* in_sizes, int n_in,
                              void* d_out, int out_size, void* d_ws, size_t ws_size,
                              hipStream_t stream) {
    const float* x      = (const float*)d_in[0];
    const int*   e0     = (const int*)  d_in[1];
    const float* W0     = (const float*)d_in[2];
    const float* b0     = (const float*)d_in[3];
    const int*   e1     = (const int*)  d_in[4];
    const float* W1     = (const float*)d_in[5];
    const float* b1     = (const float*)d_in[6];
    const int*   e2     = (const int*)  d_in[7];
    const float* W2     = (const float*)d_in[8];
    const float* b2     = (const float*)d_in[9];
    const float* alphas = (const float*)d_in[10];
    const float* Wlin   = (const float*)d_in[11];
    const float* blin   = (const float*)d_in[12];
    float* out = (float*)d_out;

    char* ws = (char*)d_ws;
    size_t off = 0;
    auto alloc = [&](size_t bytes) -> void* {
        void* p = ws + off;
        off = (off + bytes + 255) & ~(size_t)255;
        return p;
    };
    int*   cnt_out = (int*)  alloc((size_t)NG * NN * 4);
    int*   cnt_in  = (int*)  alloc((size_t)NG * NN * 4);
    int*   cursor  = (int*)  alloc((size_t)NG * NN * 4);
    int*   row_off = (int*)  alloc((size_t)NG * (NN + 1) * 4);
    int*   csr     = (int*)  alloc((size_t)NG * NE * 4);
    int*   csum    = (int*)  alloc((size_t)NG * 32 * 4);
    float* rs_out  = (float*)alloc((size_t)NG * NN * 4);
    float* rs_in   = (float*)alloc((size_t)NG * NN * 4);
    float* aptr    = (float*)alloc(16);
    float* bcat    = (float*)alloc((size_t)NG * KHID * 4);
    unsigned short* Wt  = (unsigned short*)alloc((size_t)NG * KIN * KHID * 2);
    unsigned short* Wlt = (unsigned short*)alloc((size_t)KCAT * KOUT * 2);

    const size_t SZ_Y1 = (size_t)NN * KIN * 2;     // 30.72 MB
    const size_t SZ_T  = (size_t)NN * KCAT * 2;    // 92.16 MB
    size_t remaining = (ws_size > off) ? (ws_size - off) : 0;
    int mode;
    if      (remaining >= 3 * SZ_Y1 + SZ_T + 8192)          mode = 2;  // xb aliases t
    else if (remaining >= SZ_Y1 + SZ_Y1 + SZ_T + 8192)      mode = 1;
    else                                                    mode = 0;

    unsigned short *y, *xb, *t;
    if (mode == 2) {
        y  = (unsigned short*)alloc(3 * SZ_Y1);
        t  = (unsigned short*)alloc(SZ_T);
        xb = t;
    } else if (mode == 1) {
        y  = (unsigned short*)alloc(SZ_Y1);
        xb = (unsigned short*)alloc(SZ_Y1);
        t  = (unsigned short*)alloc(SZ_T);
    } else {
        y  = (unsigned short*)alloc(SZ_Y1);
        xb = nullptr;
        t  = (unsigned short*)alloc(SZ_T);
    }

    hipMemsetAsync(cnt_out, 0, (size_t)((char*)cursor - (char*)cnt_out) + (size_t)NG * NN * 4, stream);

    k_count<<<(NG * NE + 255) / 256, 256, 0, stream>>>(e0, e1, e2, cnt_out, cnt_in);
    k_rs<<<(NG * NN + 255) / 256, 256, 0, stream>>>(cnt_out, cnt_in, rs_out, rs_in);
    k_scan1<<<dim3(NCHUNK, NG), 256, 0, stream>>>(cnt_in, csum);
    k_scan2<<<1, 192, 0, stream>>>(csum);
    k_scan3<<<dim3(NCHUNK, NG), 256, 0, stream>>>(cnt_in, csum, row_off);
    k_fill<<<(NG * NE + 255) / 256, 256, 0, stream>>>(e0, e1, e2, row_off, cursor, csr);
    k_misc<<<(NG * KHID + 255) / 256, 256, 0, stream>>>(alphas, b0, b1, b2, aptr, bcat);
    k_wt<<<NG * 256 + 384, 256, 0, stream>>>(W0, W1, W2, Wlin, Wt, Wlt);

    if (mode >= 1) {
        k_xbf<<<NN * KIN / (256 * 8), 256, 0, stream>>>(x, xb);
    }

    if (mode == 2) {
        k_agg_bf<<<dim3(NN / 4, 1, NG), 256, 0, stream>>>(
            xb, csr, row_off, rs_out, rs_in, y, (size_t)NN * KIN, 0);
        k_gemm<KIN, 512, true><<<dim3(MTILES, 1, NG), 512, 0, stream>>>(
            y, (size_t)NN * KIN, Wt, bcat, aptr, 0, t, nullptr);
    } else {
        for (int g = 0; g < NG; g++) {
            if (mode == 1)
                k_agg_bf<<<dim3(NN / 4, 1, 1), 256, 0, stream>>>(
                    xb, csr, row_off, rs_out, rs_in, y, 0, g);
            else
                k_agg_f32<<<NN / 4, 256, 0, stream>>>(x, csr, row_off, rs_out, rs_in, y, g);
            k_gemm<KIN, 512, true><<<dim3(MTILES, 1, 1), 512, 0, stream>>>(
                y, 0, Wt, bcat, aptr, g, t, nullptr);
        }
    }
    k_gemm<KCAT, 256, false><<<dim3(MTILES, 1, 1), 256, 0, stream>>>(
        t, 0, Wlt, blin, nullptr, 0, nullptr, out);
}

// Round 5
// 405.460 us; speedup vs baseline: 1.3418x; 1.0408x over previous
//
#include <hip/hip_runtime.h>

#define NN 30000      // nodes
#define NE 150000     // edges per graph
#define KIN 512
#define KHID 512
#define KOUT 256
#define NG 3
#define KCAT (KHID*NG)   // 1536
#define MTILES ((NN + 127) / 128)   // 235
#define MT64   ((NN + 63) / 64)     // 469
#define NCHUNK 30            // ceil(NN/1024)

typedef __attribute__((ext_vector_type(8))) __bf16 bf16x8;
typedef __attribute__((ext_vector_type(4))) float  f32x4;
typedef __attribute__((ext_vector_type(8))) unsigned short u16x8;

__device__ __forceinline__ unsigned short f2bf(float f) {
    unsigned u = __float_as_uint(f);
    u = (u + 0x7FFFu + ((u >> 16) & 1u)) >> 16;   // round-to-nearest-even
    return (unsigned short)u;
}
__device__ __forceinline__ float bf2f(unsigned short u) {
    return __uint_as_float((unsigned)u << 16);
}
__device__ __forceinline__ float fast_tanh(float x) {
    float e = __expf(2.f * x);
    return 1.f - __fdividef(2.f, e + 1.f);
}
__device__ __forceinline__ void gl_lds16(const void* g, void* l) {
    __builtin_amdgcn_global_load_lds(
        (const __attribute__((address_space(1))) void*)g,
        (__attribute__((address_space(3))) void*)l, 16, 0, 0);
}

// ---------- degree histogram ----------
__global__ void k_count(const int* __restrict__ e0, const int* __restrict__ e1,
                        const int* __restrict__ e2, int* cnt_out, int* cnt_in) {
    int idx = blockIdx.x * 256 + threadIdx.x;
    if (idx >= NG * NE) return;
    int g = idx / NE, e = idx - g * NE;
    const int* ed = (g == 0) ? e0 : ((g == 1) ? e1 : e2);
    atomicAdd(&cnt_out[g * NN + ed[e]], 1);
    atomicAdd(&cnt_in [g * NN + ed[NE + e]], 1);
}

// ---------- rsqrt(clip(deg,1)) ----------
__global__ void k_rs(const int* cnt_out, const int* cnt_in, float* rs_out, float* rs_in) {
    int idx = blockIdx.x * 256 + threadIdx.x;
    if (idx >= NG * NN) return;
    int co = cnt_out[idx]; if (co < 1) co = 1;
    int ci = cnt_in [idx]; if (ci < 1) ci = 1;
    rs_out[idx] = rsqrtf((float)co);
    rs_in [idx] = rsqrtf((float)ci);
}

// ---------- parallel scan, phase 1: per-1024-chunk sums ----------
__global__ __launch_bounds__(256) void k_scan1(const int* __restrict__ cnt_in,
                                               int* __restrict__ csum) {
    int g = blockIdx.y, c = blockIdx.x;
    const int* cc = cnt_in + g * NN;
    int i = c * 1024 + threadIdx.x * 4;
    int4 v = {0, 0, 0, 0};
    if (i + 3 < NN) v = *(const int4*)(cc + i);
    else {
        if (i     < NN) v.x = cc[i];
        if (i + 1 < NN) v.y = cc[i + 1];
        if (i + 2 < NN) v.z = cc[i + 2];
        if (i + 3 < NN) v.w = cc[i + 3];
    }
    int s = v.x + v.y + v.z + v.w;
    #pragma unroll
    for (int o = 32; o > 0; o >>= 1) s += __shfl_down(s, o, 64);
    __shared__ int ws[4];
    if ((threadIdx.x & 63) == 0) ws[threadIdx.x >> 6] = s;
    __syncthreads();
    if (threadIdx.x == 0) csum[g * 32 + c] = ws[0] + ws[1] + ws[2] + ws[3];
}

// ---------- phase 2: exclusive scan of the 30 chunk sums (one wave per graph) ----------
__global__ void k_scan2(int* __restrict__ csum) {
    int g = threadIdx.x >> 6, lane = threadIdx.x & 63;
    if (g >= NG) return;
    int v = (lane < NCHUNK) ? csum[g * 32 + lane] : 0;
    int inc = v;
    #pragma unroll
    for (int o = 1; o < 32; o <<= 1) {
        int n = __shfl_up(inc, o, 64);
        if (lane >= o) inc += n;
    }
    if (lane < NCHUNK) csum[g * 32 + lane] = inc - v;
}

// ---------- phase 3: in-chunk scan + base -> row_off ----------
__global__ __launch_bounds__(256) void k_scan3(const int* __restrict__ cnt_in,
        const int* __restrict__ csum, int* __restrict__ row_off) {
    int g = blockIdx.y, c = blockIdx.x;
    const int* cc = cnt_in + g * NN;
    int* ro = row_off + g * (NN + 1);
    int tid = threadIdx.x, lane = tid & 63, w = tid >> 6;
    int i = c * 1024 + tid * 4;
    int4 v = {0, 0, 0, 0};
    if (i + 3 < NN) v = *(const int4*)(cc + i);
    else {
        if (i     < NN) v.x = cc[i];
        if (i + 1 < NN) v.y = cc[i + 1];
        if (i + 2 < NN) v.z = cc[i + 2];
        if (i + 3 < NN) v.w = cc[i + 3];
    }
    int s = v.x + v.y + v.z + v.w;
    int inc = s;
    #pragma unroll
    for (int o = 1; o < 64; o <<= 1) {
        int n = __shfl_up(inc, o, 64);
        if (lane >= o) inc += n;
    }
    __shared__ int ws[4];
    if (lane == 63) ws[w] = inc;
    __syncthreads();
    int base = csum[g * 32 + c];
    for (int k = 0; k < w; k++) base += ws[k];
    int excl = base + inc - s;
    if (i     < NN) ro[i]     = excl;
    if (i + 1 < NN) ro[i + 1] = excl + v.x;
    if (i + 2 < NN) ro[i + 2] = excl + v.x + v.y;
    if (i + 3 < NN) ro[i + 3] = excl + v.x + v.y + v.z;
    if (c == 0 && tid == 0) ro[NN] = NE;
}

// ---------- CSR fill ----------
__global__ void k_fill(const int* __restrict__ e0, const int* __restrict__ e1,
                       const int* __restrict__ e2, const int* __restrict__ row_off,
                       int* cursor, int* __restrict__ csr) {
    int idx = blockIdx.x * 256 + threadIdx.x;
    if (idx >= NG * NE) return;
    int g = idx / NE, e = idx - g * NE;
    const int* ed = (g == 0) ? e0 : ((g == 1) ? e1 : e2);
    int s = ed[e], d = ed[NE + e];
    int pos = atomicAdd(&cursor[g * NN + d], 1);
    csr[g * NE + row_off[g * (NN + 1) + d] + pos] = s;
}

// ---------- softmax(alphas) + pack branch biases contiguous ----------
__global__ void k_misc(const float* __restrict__ alphas,
                       const float* __restrict__ b0, const float* __restrict__ b1,
                       const float* __restrict__ b2, float* __restrict__ aptr,
                       float* __restrict__ bcat) {
    int idx = blockIdx.x * 256 + threadIdx.x;
    if (idx < NG * KHID) {
        int g = idx >> 9;
        const float* b = (g == 0) ? b0 : ((g == 1) ? b1 : b2);
        bcat[idx] = b[idx & 511];
    }
    if (idx == 0) {
        float m = fmaxf(alphas[0], fmaxf(alphas[1], alphas[2]));
        float ex0 = expf(alphas[0] - m), ex1 = expf(alphas[1] - m), ex2 = expf(alphas[2] - m);
        float s = ex0 + ex1 + ex2;
        aptr[0] = ex0 / s; aptr[1] = ex1 / s; aptr[2] = ex2 / s;
    }
}

// ---------- weights -> bf16 transposed [n][k], coalesced via 32x32 LDS tile ----------
__global__ __launch_bounds__(256) void k_wt(const float* __restrict__ W0,
        const float* __restrict__ W1, const float* __restrict__ W2,
        const float* __restrict__ Wlin,
        unsigned short* __restrict__ Wt, unsigned short* __restrict__ Wlt) {
    __shared__ float Ls[32][33];
    int bid = blockIdx.x;
    const float* src; unsigned short* dst; int ncols, kdim, k0, n0;
    if (bid < NG * 256) {
        int g = bid >> 8, t = bid & 255;
        int kt = t >> 4, nt = t & 15;
        src = (g == 0) ? W0 : ((g == 1) ? W1 : W2);
        dst = Wt + (size_t)g * KIN * KHID;
        ncols = KHID; kdim = KIN; k0 = kt * 32; n0 = nt * 32;
    } else {
        int t = bid - NG * 256;
        int kt = t % 48, nt = t / 48;
        src = Wlin; dst = Wlt; ncols = KOUT; kdim = KCAT; k0 = kt * 32; n0 = nt * 32;
    }
    int tid = threadIdx.x;
    int r = tid >> 3, c4 = (tid & 7) * 4;
    float4 v = *(const float4*)(src + (size_t)(k0 + r) * ncols + n0 + c4);
    Ls[r][c4 + 0] = v.x; Ls[r][c4 + 1] = v.y; Ls[r][c4 + 2] = v.z; Ls[r][c4 + 3] = v.w;
    __syncthreads();
    int nr = tid >> 3, kc = (tid & 7) * 4;
    ushort4 o;
    o.x = f2bf(Ls[kc + 0][nr]); o.y = f2bf(Ls[kc + 1][nr]);
    o.z = f2bf(Ls[kc + 2][nr]); o.w = f2bf(Ls[kc + 3][nr]);
    *(ushort4*)(dst + (size_t)(n0 + nr) * kdim + k0 + kc) = o;
}

// ---------- x -> bf16 ----------
__global__ void k_xbf(const float* __restrict__ x, unsigned short* __restrict__ xb) {
    size_t i = ((size_t)blockIdx.x * 256 + threadIdx.x) * 8;
    float4 v0 = *(const float4*)(x + i);
    float4 v1 = *(const float4*)(x + i + 4);
    uint4 pk;
    pk.x = (unsigned)f2bf(v0.x) | ((unsigned)f2bf(v0.y) << 16);
    pk.y = (unsigned)f2bf(v0.z) | ((unsigned)f2bf(v0.w) << 16);
    pk.z = (unsigned)f2bf(v1.x) | ((unsigned)f2bf(v1.y) << 16);
    pk.w = (unsigned)f2bf(v1.z) | ((unsigned)f2bf(v1.w) << 16);
    *(uint4*)(xb + i) = pk;
}

// ---------- aggregation (bf16 x), 4 independent gather chains ----------
__global__ __launch_bounds__(256) void k_agg_bf(const unsigned short* __restrict__ xb,
        const int* __restrict__ csr, const int* __restrict__ row_off,
        const float* __restrict__ rs_out, const float* __restrict__ rs_in,
        unsigned short* __restrict__ y, size_t ystride, int gbase) {
    int g    = gbase + blockIdx.z;
    int d    = blockIdx.x * 4 + (threadIdx.x >> 6);
    int lane = threadIdx.x & 63;
    int beg = row_off[g * (NN + 1) + d];
    int end = row_off[g * (NN + 1) + d + 1];
    const int* cs = csr + g * NE;
    const float* rso = rs_out + g * NN;
    float a0=0,a1=0,a2=0,a3=0,a4=0,a5=0,a6=0,a7=0;
    const unsigned short* xbl = xb + lane * 8;
    int e = beg;
    for (; e + 3 < end; e += 4) {       // four independent gather chains
        int s0 = cs[e], s1 = cs[e+1], s2 = cs[e+2], s3 = cs[e+3];
        float w0 = rso[s0], w1 = rso[s1], w2 = rso[s2], w3 = rso[s3];
        u16x8 v0 = *(const u16x8*)(xbl + (size_t)s0 * KIN);
        u16x8 v1 = *(const u16x8*)(xbl + (size_t)s1 * KIN);
        u16x8 v2 = *(const u16x8*)(xbl + (size_t)s2 * KIN);
        u16x8 v3 = *(const u16x8*)(xbl + (size_t)s3 * KIN);
        a0 += w0*bf2f(v0[0]) + w1*bf2f(v1[0]) + w2*bf2f(v2[0]) + w3*bf2f(v3[0]);
        a1 += w0*bf2f(v0[1]) + w1*bf2f(v1[1]) + w2*bf2f(v2[1]) + w3*bf2f(v3[1]);
        a2 += w0*bf2f(v0[2]) + w1*bf2f(v1[2]) + w2*bf2f(v2[2]) + w3*bf2f(v3[2]);
        a3 += w0*bf2f(v0[3]) + w1*bf2f(v1[3]) + w2*bf2f(v2[3]) + w3*bf2f(v3[3]);
        a4 += w0*bf2f(v0[4]) + w1*bf2f(v1[4]) + w2*bf2f(v2[4]) + w3*bf2f(v3[4]);
        a5 += w0*bf2f(v0[5]) + w1*bf2f(v1[5]) + w2*bf2f(v2[5]) + w3*bf2f(v3[5]);
        a6 += w0*bf2f(v0[6]) + w1*bf2f(v1[6]) + w2*bf2f(v2[6]) + w3*bf2f(v3[6]);
        a7 += w0*bf2f(v0[7]) + w1*bf2f(v1[7]) + w2*bf2f(v2[7]) + w3*bf2f(v3[7]);
    }
    for (; e < end; e++) {
        int s0 = cs[e];
        float w0 = rso[s0];
        u16x8 v0 = *(const u16x8*)(xbl + (size_t)s0 * KIN);
        a0 += w0 * bf2f(v0[0]); a1 += w0 * bf2f(v0[1]);
        a2 += w0 * bf2f(v0[2]); a3 += w0 * bf2f(v0[3]);
        a4 += w0 * bf2f(v0[4]); a5 += w0 * bf2f(v0[5]);
        a6 += w0 * bf2f(v0[6]); a7 += w0 * bf2f(v0[7]);
    }
    float ri = rs_in[g * NN + d];
    uint4 pk;
    pk.x = (unsigned)f2bf(a0 * ri) | ((unsigned)f2bf(a1 * ri) << 16);
    pk.y = (unsigned)f2bf(a2 * ri) | ((unsigned)f2bf(a3 * ri) << 16);
    pk.z = (unsigned)f2bf(a4 * ri) | ((unsigned)f2bf(a5 * ri) << 16);
    pk.w = (unsigned)f2bf(a6 * ri) | ((unsigned)f2bf(a7 * ri) << 16);
    *(uint4*)(y + (size_t)g * ystride + (size_t)d * KIN + lane * 8) = pk;
}

// ---------- aggregation (fp32 x fallback) ----------
__global__ __launch_bounds__(256) void k_agg_f32(const float* __restrict__ x,
        const int* __restrict__ csr, const int* __restrict__ row_off,
        const float* __restrict__ rs_out, const float* __restrict__ rs_in,
        unsigned short* __restrict__ y, int g) {
    int d    = blockIdx.x * 4 + (threadIdx.x >> 6);
    int lane = threadIdx.x & 63;
    int beg = row_off[g * (NN + 1) + d];
    int end = row_off[g * (NN + 1) + d + 1];
    const int* cs = csr + g * NE;
    float a0=0,a1=0,a2=0,a3=0,a4=0,a5=0,a6=0,a7=0;
    const float* xb = x + lane * 8;
    for (int e = beg; e < end; e++) {
        int s = cs[e];
        float wsc = rs_out[g * NN + s];
        const float4* xr = (const float4*)(xb + (size_t)s * KIN);
        float4 v0 = xr[0], v1 = xr[1];
        a0 += wsc * v0.x; a1 += wsc * v0.y; a2 += wsc * v0.z; a3 += wsc * v0.w;
        a4 += wsc * v1.x; a5 += wsc * v1.y; a6 += wsc * v1.z; a7 += wsc * v1.w;
    }
    float ri = rs_in[g * NN + d];
    uint4 pk;
    pk.x = (unsigned)f2bf(a0 * ri) | ((unsigned)f2bf(a1 * ri) << 16);
    pk.y = (unsigned)f2bf(a2 * ri) | ((unsigned)f2bf(a3 * ri) << 16);
    pk.z = (unsigned)f2bf(a4 * ri) | ((unsigned)f2bf(a5 * ri) << 16);
    pk.w = (unsigned)f2bf(a6 * ri) | ((unsigned)f2bf(a7 * ri) << 16);
    *(uint4*)(y + (size_t)d * KIN + lane * 8) = pk;
}

// ---------- BM x BN MFMA GEMM, 4 waves (64x64 wave tile), XOR-swizzled LDS,
//            double-buffered (1 barrier/iter), small LDS for high blocks/CU ----------
// grid: (BNgrid, Mtiles, graphs). gemm1: BM=128,BN=128 -> 32 KB LDS, 5 blocks/CU.
//       gemm2: BM=64, BN=256 -> 40 KB LDS, 4 blocks/CU, grid 469 m-tiles.
template<int KDIM, int BM, int BN, bool TANH>
__global__ __launch_bounds__(256) void k_gemm(const unsigned short* __restrict__ A,
        size_t agstride, const unsigned short* __restrict__ Bt,
        const float* __restrict__ bias, const float* __restrict__ aptr, int gbase,
        unsigned short* __restrict__ Tout, float* __restrict__ Fout) {
    constexpr int NITER = KDIM / 32;
    constexpr int ACH = BM * 4 / 256;          // A 16B-chunks per thread
    constexpr int BCH = BN * 4 / 256;          // B 16B-chunks per thread
    constexpr int MQ = BM / 64;                // waves along m
    __shared__ __align__(16) unsigned short As[2][BM * 32];
    __shared__ __align__(16) unsigned short Bs[2][BN * 32];
    int g = gbase + blockIdx.z;
    const unsigned short* Ab = A + (size_t)g * agstride;
    const unsigned short* Bb = (TANH ? (Bt + (size_t)g * KIN * KHID) : Bt);
    const float* bb = TANH ? (bias + g * KHID) : bias;
    int m0 = blockIdx.y * BM;
    int n0 = blockIdx.x * BN;
    int tid = threadIdx.x, lane = tid & 63, w = tid >> 6;
    int mq = w % MQ, nq = w / MQ;              // wave = 64m x 64n subtile

    f32x4 acc[4][4];
    #pragma unroll
    for (int i = 0; i < 4; i++)
        #pragma unroll
        for (int j = 0; j < 4; j++) acc[i][j] = (f32x4){0.f, 0.f, 0.f, 0.f};

    // staging pointers; chunk c holds global column-chunk (c&3)^((c>>3)&3) of row c>>2
    const unsigned short* Ag[ACH];
    unsigned short* Al[ACH];
    #pragma unroll
    for (int j = 0; j < ACH; j++) {
        int c = tid + 256 * j;
        int r = c >> 2, q = (c & 3) ^ ((c >> 3) & 3);
        int grow = m0 + r; if (grow >= NN) grow = NN - 1;
        Ag[j] = Ab + (size_t)grow * KDIM + q * 8;
        Al[j] = (unsigned short*)&As[0][c * 8];
    }
    const unsigned short* Bg[BCH];
    unsigned short* Bl[BCH];
    #pragma unroll
    for (int j = 0; j < BCH; j++) {
        int c = tid + 256 * j;
        int r = c >> 2, q = (c & 3) ^ ((c >> 3) & 3);
        Bg[j] = Bb + (size_t)(n0 + r) * KDIM + q * 8;
        Bl[j] = (unsigned short*)&Bs[0][c * 8];
    }
    constexpr int ABUF = BM * 32, BBUF = BN * 32;

    auto stage = [&](int buf, int k0) {
        #pragma unroll
        for (int j = 0; j < ACH; j++) gl_lds16(Ag[j] + k0, Al[j] + buf * ABUF);
        #pragma unroll
        for (int j = 0; j < BCH; j++) gl_lds16(Bg[j] + k0, Bl[j] + buf * BBUF);
    };

    // fragment read offsets; kqs folds the XOR swizzle (uniform over mi/ni since
    // row bases are multiples of 8 -> (row>>1)&3 depends only on lane&15)
    int kqs = (((lane >> 4) ^ ((lane >> 1) & 3))) * 8;
    int arow = mq * 64 + (lane & 15);
    int nrow = nq * 64 + (lane & 15);

    stage(0, 0);
    for (int it = 0; it < NITER; it++) {
        __syncthreads();
        if (it + 1 < NITER) stage((it + 1) & 1, (it + 1) * 32);
        const unsigned short* Alb = As[it & 1];
        const unsigned short* Blb = Bs[it & 1];
        bf16x8 af[4], bfr[4];
        #pragma unroll
        for (int mi = 0; mi < 4; mi++) af[mi] = *(const bf16x8*)&Alb[(arow + mi * 16) * 32 + kqs];
        #pragma unroll
        for (int ni = 0; ni < 4; ni++) bfr[ni] = *(const bf16x8*)&Blb[(nrow + ni * 16) * 32 + kqs];
        #pragma unroll
        for (int mi = 0; mi < 4; mi++)
            #pragma unroll
            for (int ni = 0; ni < 4; ni++)
                acc[mi][ni] = __builtin_amdgcn_mfma_f32_16x16x32_bf16(af[mi], bfr[ni], acc[mi][ni], 0, 0, 0);
    }

    float ascale = TANH ? aptr[g] : 0.f;
    int rb = mq * 64 + (lane >> 4) * 4;
    #pragma unroll
    for (int mi = 0; mi < 4; mi++) {
        #pragma unroll
        for (int r = 0; r < 4; r++) {
            int row = m0 + rb + mi * 16 + r;
            if (row < NN) {
                #pragma unroll
                for (int ni = 0; ni < 4; ni++) {
                    int col = n0 + nq * 64 + ni * 16 + (lane & 15);
                    float v = acc[mi][ni][r] + bb[col];
                    if (TANH) {
                        Tout[(size_t)row * KCAT + g * KHID + col] = f2bf(fast_tanh(ascale * v));
                    } else {
                        Fout[(size_t)row * KOUT + col] = v;
                    }
                }
            }
        }
    }
}

extern "C" void kernel_launch(void* const* d_in, const int* in_sizes, int n_in,
                              void* d_out, int out_size, void* d_ws, size_t ws_size,
                              hipStream_t stream) {
    const float* x      = (const float*)d_in[0];
    const int*   e0     = (const int*)  d_in[1];
    const float* W0     = (const float*)d_in[2];
    const float* b0     = (const float*)d_in[3];
    const int*   e1     = (const int*)  d_in[4];
    const float* W1     = (const float*)d_in[5];
    const float* b1     = (const float*)d_in[6];
    const int*   e2     = (const int*)  d_in[7];
    const float* W2     = (const float*)d_in[8];
    const float* b2     = (const float*)d_in[9];
    const float* alphas = (const float*)d_in[10];
    const float* Wlin   = (const float*)d_in[11];
    const float* blin   = (const float*)d_in[12];
    float* out = (float*)d_out;

    char* ws = (char*)d_ws;
    size_t off = 0;
    auto alloc = [&](size_t bytes) -> void* {
        void* p = ws + off;
        off = (off + bytes + 255) & ~(size_t)255;
        return p;
    };
    int*   cnt_out = (int*)  alloc((size_t)NG * NN * 4);
    int*   cnt_in  = (int*)  alloc((size_t)NG * NN * 4);
    int*   cursor  = (int*)  alloc((size_t)NG * NN * 4);
    int*   row_off = (int*)  alloc((size_t)NG * (NN + 1) * 4);
    int*   csr     = (int*)  alloc((size_t)NG * NE * 4);
    int*   csum    = (int*)  alloc((size_t)NG * 32 * 4);
    float* rs_out  = (float*)alloc((size_t)NG * NN * 4);
    float* rs_in   = (float*)alloc((size_t)NG * NN * 4);
    float* aptr    = (float*)alloc(16);
    float* bcat    = (float*)alloc((size_t)NG * KHID * 4);
    unsigned short* Wt  = (unsigned short*)alloc((size_t)NG * KIN * KHID * 2);
    unsigned short* Wlt = (unsigned short*)alloc((size_t)KCAT * KOUT * 2);

    const size_t SZ_Y1 = (size_t)NN * KIN * 2;     // 30.72 MB
    const size_t SZ_T  = (size_t)NN * KCAT * 2;    // 92.16 MB
    size_t remaining = (ws_size > off) ? (ws_size - off) : 0;
    int mode;
    if      (remaining >= 3 * SZ_Y1 + SZ_T + 8192)          mode = 2;  // xb aliases t
    else if (remaining >= SZ_Y1 + SZ_Y1 + SZ_T + 8192)      mode = 1;
    else                                                    mode = 0;

    unsigned short *y, *xb, *t;
    if (mode == 2) {
        y  = (unsigned short*)alloc(3 * SZ_Y1);
        t  = (unsigned short*)alloc(SZ_T);
        xb = t;
    } else if (mode == 1) {
        y  = (unsigned short*)alloc(SZ_Y1);
        xb = (unsigned short*)alloc(SZ_Y1);
        t  = (unsigned short*)alloc(SZ_T);
    } else {
        y  = (unsigned short*)alloc(SZ_Y1);
        xb = nullptr;
        t  = (unsigned short*)alloc(SZ_T);
    }

    hipMemsetAsync(cnt_out, 0, (size_t)((char*)cursor - (char*)cnt_out) + (size_t)NG * NN * 4, stream);

    k_count<<<(NG * NE + 255) / 256, 256, 0, stream>>>(e0, e1, e2, cnt_out, cnt_in);
    k_rs<<<(NG * NN + 255) / 256, 256, 0, stream>>>(cnt_out, cnt_in, rs_out, rs_in);
    k_scan1<<<dim3(NCHUNK, NG), 256, 0, stream>>>(cnt_in, csum);
    k_scan2<<<1, 192, 0, stream>>>(csum);
    k_scan3<<<dim3(NCHUNK, NG), 256, 0, stream>>>(cnt_in, csum, row_off);
    k_fill<<<(NG * NE + 255) / 256, 256, 0, stream>>>(e0, e1, e2, row_off, cursor, csr);
    k_misc<<<(NG * KHID + 255) / 256, 256, 0, stream>>>(alphas, b0, b1, b2, aptr, bcat);
    k_wt<<<NG * 256 + 384, 256, 0, stream>>>(W0, W1, W2, Wlin, Wt, Wlt);

    if (mode >= 1) {
        k_xbf<<<NN * KIN / (256 * 8), 256, 0, stream>>>(x, xb);
    }

    if (mode == 2) {
        k_agg_bf<<<dim3(NN / 4, 1, NG), 256, 0, stream>>>(
            xb, csr, row_off, rs_out, rs_in, y, (size_t)NN * KIN, 0);
        k_gemm<KIN, 128, 128, true><<<dim3(KHID / 128, MTILES, NG), 256, 0, stream>>>(
            y, (size_t)NN * KIN, Wt, bcat, aptr, 0, t, nullptr);
    } else {
        for (int g = 0; g < NG; g++) {
            if (mode == 1)
                k_agg_bf<<<dim3(NN / 4, 1, 1), 256, 0, stream>>>(
                    xb, csr, row_off, rs_out, rs_in, y, 0, g);
            else
                k_agg_f32<<<NN / 4, 256, 0, stream>>>(x, csr, row_off, rs_out, rs_in, y, g);
            k_gemm<KIN, 128, 128, true><<<dim3(KHID / 128, MTILES, 1), 256, 0, stream>>>(
                y, 0, Wt, bcat, aptr, g, t, nullptr);
        }
    }
    k_gemm<KCAT, 64, 256, false><<<dim3(1, MT64, 1), 256, 0, stream>>>(
        t, 0, Wlt, blin, nullptr, 0, nullptr, out);
}